// Round 1
// baseline (4447.927 us; speedup 1.0000x reference)
//
#include <hip/hip_runtime.h>
#include <cstdio>
#include <math.h>

static constexpr int B_ = 64, N_ = 200, H_ = 256, NH_ = 8, G_ = 2, L_ = 3, F_ = 512;
static constexpr int BN_ = B_ * N_;  // 12800

__device__ __forceinline__ float wave_sum64(float v) {
#pragma unroll
  for (int off = 32; off; off >>= 1) v += __shfl_xor(v, off);
  return v;
}
__device__ __forceinline__ float wave_max64(float v) {
#pragma unroll
  for (int off = 32; off; off >>= 1) v = fmaxf(v, __shfl_xor(v, off));
  return v;
}
__device__ __forceinline__ float sigmoidf_(float x) { return 1.f / (1.f + __expf(-x)); }

// ---------------- generic tiled f32 GEMM: C = act(A@B + bias + res) ----------------
// A[M,K] lda, B[K,N] ldb, C[M,N] ldc. res has same layout as C. ACT: 0=none 1=relu
template <int ACT, bool HAS_BIAS, bool HAS_RES>
__global__ __launch_bounds__(256) void gemm_f32(
    const float* __restrict__ A, const float* __restrict__ B,
    const float* __restrict__ bias, const float* __restrict__ res,
    float* __restrict__ C, int M, int N, int K, int lda, int ldb, int ldc) {
  __shared__ float As[16][65];
  __shared__ float Bs[16][65];
  const int m0 = blockIdx.x * 64;
  const int n0 = blockIdx.y * 64;
  const int tid = threadIdx.x;
  const int tx = tid & 15, ty = tid >> 4;
  float acc[4][4] = {};
  for (int k0 = 0; k0 < K; k0 += 16) {
    {  // A tile 64x16
      const int e = tid * 4;
      const int row = e >> 4, kk = e & 15;
      const int gm = m0 + row;
#pragma unroll
      for (int u = 0; u < 4; ++u) {
        const int gk = k0 + kk + u;
        As[kk + u][row] = (gm < M && gk < K) ? A[(long)gm * lda + gk] : 0.f;
      }
    }
    {  // B tile 16x64
      const int e = tid * 4;
      const int kk = e >> 6, col = e & 63;
      const int gk = k0 + kk;
#pragma unroll
      for (int u = 0; u < 4; ++u) {
        const int gn = n0 + col + u;
        Bs[kk][col + u] = (gk < K && gn < N) ? B[(long)gk * ldb + gn] : 0.f;
      }
    }
    __syncthreads();
#pragma unroll
    for (int kk = 0; kk < 16; ++kk) {
      float a[4], b[4];
#pragma unroll
      for (int i = 0; i < 4; ++i) a[i] = As[kk][ty * 4 + i];
#pragma unroll
      for (int j = 0; j < 4; ++j) b[j] = Bs[kk][tx * 4 + j];
#pragma unroll
      for (int i = 0; i < 4; ++i)
#pragma unroll
        for (int j = 0; j < 4; ++j) acc[i][j] += a[i] * b[j];
    }
    __syncthreads();
  }
#pragma unroll
  for (int i = 0; i < 4; ++i) {
    const int gm = m0 + ty * 4 + i;
    if (gm >= M) continue;
#pragma unroll
    for (int j = 0; j < 4; ++j) {
      const int gn = n0 + tx * 4 + j;
      if (gn >= N) continue;
      float v = acc[i][j];
      if (HAS_BIAS) v += bias[gn];
      if (HAS_RES) v += res[(long)gm * ldc + gn];
      if (ACT == 1) v = fmaxf(v, 0.f);
      C[(long)gm * ldc + gn] = v;
    }
  }
}

// ---------------- GAT: per-head attention vectors a_src/a_dst ----------------
// xp [BN, 2048]; att_* [NH*H] (already offset by g). out a_* [BN, NH]
__global__ __launch_bounds__(256) void gat_attvec(
    const float* __restrict__ xp, const float* __restrict__ att_src,
    const float* __restrict__ att_dst, float* __restrict__ a_src,
    float* __restrict__ a_dst) {
  const int bn = blockIdx.x;
  const int t = threadIdx.x;
  const int h = t >> 5, s = t & 31;
  const float* xr = xp + (long)bn * 2048 + h * 256 + s * 8;
  const float* vs = att_src + h * 256 + s * 8;
  const float* vd = att_dst + h * 256 + s * 8;
  float ps = 0.f, pd = 0.f;
#pragma unroll
  for (int u = 0; u < 8; ++u) {
    const float x = xr[u];
    ps += x * vs[u];
    pd += x * vd[u];
  }
#pragma unroll
  for (int off = 16; off; off >>= 1) {
    ps += __shfl_xor(ps, off);
    pd += __shfl_xor(pd, off);
  }
  if (s == 0) {
    a_src[bn * 8 + h] = ps;
    a_dst[bn * 8 + h] = pd;
  }
}

// ---------------- GAT: masked leaky-relu softmax over sources ----------------
// block id = (b*N + j)*8 + h, 64 threads. adj[b,i,j]; mask ok = (i==j)||adj>0
// out attn[(b*8+h), j, i]
__global__ __launch_bounds__(64) void gat_attn_softmax(
    const float* __restrict__ a_src, const float* __restrict__ a_dst,
    const int* __restrict__ adj, float* __restrict__ attn) {
  const int id = blockIdx.x;
  const int h = id & 7;
  const int bj = id >> 3;
  const int j = bj % N_, b = bj / N_;
  const float ad = a_dst[bj * 8 + h];
  const int lane = threadIdx.x;
  float vals[4];
  float mx = -1e30f;
#pragma unroll
  for (int r = 0; r < 4; ++r) {
    const int i = lane + r * 64;
    float v = -1e30f;
    if (i < N_) {
      float x = ad + a_src[(b * N_ + i) * 8 + h];
      x = x > 0.f ? x : 0.2f * x;
      const bool ok = (i == j) || (adj[(long)b * N_ * N_ + (long)i * N_ + j] > 0);
      v = ok ? x : -1e9f;
    }
    vals[r] = v;
    mx = fmaxf(mx, v);
  }
  mx = wave_max64(mx);
  float sum = 0.f;
#pragma unroll
  for (int r = 0; r < 4; ++r) {
    const int i = lane + r * 64;
    if (i < N_) {
      const float e = __expf(vals[r] - mx);
      vals[r] = e;
      sum += e;
    }
  }
  sum = wave_sum64(sum);
  const float inv = 1.f / sum;
  float* row = attn + ((long)(b * 8 + h) * N_ + j) * N_;
#pragma unroll
  for (int r = 0; r < 4; ++r) {
    const int i = lane + r * 64;
    if (i < N_) row[i] = vals[r] * inv;
  }
}

// ---------------- GAT message: x_out = x_in + relu(mean_h(attn_h @ xp_h) + bias) --------
// attn [B*8, N, N]; xp [B, N, 2048]; out/in [B, N, 256]
__global__ __launch_bounds__(256) void gat_msg(
    const float* __restrict__ attn, const float* __restrict__ xp,
    const float* __restrict__ bias, const float* __restrict__ xin,
    float* __restrict__ xout) {
  __shared__ float As[16][65];
  __shared__ float Bs[16][65];
  const int j0 = blockIdx.x * 64;
  const int d0 = blockIdx.y * 64;
  const int b = blockIdx.z;
  const int tid = threadIdx.x;
  const int tx = tid & 15, ty = tid >> 4;
  float acc[4][4] = {};
  for (int h = 0; h < 8; ++h) {
    const float* Ab = attn + (long)(b * 8 + h) * N_ * N_;
    const float* Bb = xp + (long)b * N_ * 2048 + h * 256;
    for (int k0 = 0; k0 < N_; k0 += 16) {
      {
        const int e = tid * 4;
        const int row = e >> 4, kk = e & 15;
        const int gj = j0 + row;
#pragma unroll
        for (int u = 0; u < 4; ++u) {
          const int gk = k0 + kk + u;
          As[kk + u][row] = (gj < N_ && gk < N_) ? Ab[(long)gj * N_ + gk] : 0.f;
        }
      }
      {
        const int e = tid * 4;
        const int kk = e >> 6, col = e & 63;
        const int gk = k0 + kk;
#pragma unroll
        for (int u = 0; u < 4; ++u)
          Bs[kk][col + u] = (gk < N_) ? Bb[(long)gk * 2048 + d0 + col + u] : 0.f;
      }
      __syncthreads();
#pragma unroll
      for (int kk = 0; kk < 16; ++kk) {
        float a[4], bv[4];
#pragma unroll
        for (int i = 0; i < 4; ++i) a[i] = As[kk][ty * 4 + i];
#pragma unroll
        for (int j = 0; j < 4; ++j) bv[j] = Bs[kk][tx * 4 + j];
#pragma unroll
        for (int i = 0; i < 4; ++i)
#pragma unroll
          for (int j = 0; j < 4; ++j) acc[i][j] += a[i] * bv[j];
      }
      __syncthreads();
    }
  }
#pragma unroll
  for (int i = 0; i < 4; ++i) {
    const int gj = j0 + ty * 4 + i;
    if (gj >= N_) continue;
#pragma unroll
    for (int j = 0; j < 4; ++j) {
      const int gd = d0 + tx * 4 + j;
      const float m = acc[i][j] * 0.125f + bias[gd];
      const long o = (long)(b * N_ + gj) * 256 + gd;
      xout[o] = xin[o] + fmaxf(m, 0.f);
    }
  }
}

// ---------------- LayerNorm over last dim 256; PRE=1: in = in1 + relu(in2) ----------
template <int PRE>
__global__ __launch_bounds__(256) void ln_kernel(
    const float* __restrict__ in1, const float* __restrict__ in2,
    const float* __restrict__ sb, float* __restrict__ out) {
  const int row = blockIdx.x, t = threadIdx.x;
  const long o = (long)row * 256 + t;
  const float v = PRE ? (in1[o] + fmaxf(in2[o], 0.f)) : in1[o];
  float s = v, q = v * v;
#pragma unroll
  for (int off = 32; off; off >>= 1) {
    s += __shfl_xor(s, off);
    q += __shfl_xor(q, off);
  }
  __shared__ float sh[8];
  const int wid = t >> 6, lane = t & 63;
  if (lane == 0) {
    sh[wid] = s;
    sh[4 + wid] = q;
  }
  __syncthreads();
  const float S = sh[0] + sh[1] + sh[2] + sh[3];
  const float Q = sh[4] + sh[5] + sh[6] + sh[7];
  const float mean = S * (1.f / 256.f);
  const float var = Q * (1.f / 256.f) - mean * mean;
  const float r = rsqrtf(var + 1e-5f);
  out[o] = (v - mean) * r * sb[t] + sb[256 + t];
}

// ---------------- encoder: scores + masked softmax -> at[(b*8+h), q, k] -------------
__global__ __launch_bounds__(64) void attn_score_softmax(
    const float* __restrict__ qb, const float* __restrict__ kb,
    const int* __restrict__ adj, float* __restrict__ at) {
  const int id = blockIdx.x;  // (b*8+h)*N + qi
  const int qi = id % N_;
  const int bh = id / N_;
  const int b = bh >> 3, h = bh & 7;
  __shared__ float qs[32];
  const int lane = threadIdx.x;
  if (lane < 32) qs[lane] = qb[(long)(b * N_ + qi) * 256 + h * 32 + lane];
  __syncthreads();
  const int* arow = adj + (long)b * N_ * N_ + (long)qi * N_;
  float vals[4];
  float mx = -1e30f;
#pragma unroll
  for (int r = 0; r < 4; ++r) {
    const int ki = lane + r * 64;
    float v = -1e30f;
    if (ki < N_) {
      if (arow[ki] > 0) {
        const float* kv = kb + (long)(b * N_ + ki) * 256 + h * 32;
        float dot = 0.f;
#pragma unroll
        for (int d = 0; d < 32; ++d) dot += qs[d] * kv[d];
        v = dot * 0.17677669529663687f;  // 1/sqrt(32)
      } else {
        v = -1e9f;
      }
    }
    vals[r] = v;
    mx = fmaxf(mx, v);
  }
  mx = wave_max64(mx);
  float sum = 0.f;
#pragma unroll
  for (int r = 0; r < 4; ++r) {
    const int ki = lane + r * 64;
    if (ki < N_) {
      const float e = __expf(vals[r] - mx);
      vals[r] = e;
      sum += e;
    }
  }
  sum = wave_sum64(sum);
  const float inv = 1.f / sum;
  float* row = at + ((long)bh * N_ + qi) * N_;
#pragma unroll
  for (int r = 0; r < 4; ++r) {
    const int ki = lane + r * 64;
    if (ki < N_) row[ki] = vals[r] * inv;
  }
}

// ---------------- encoder: ctx[(b,q,h*32+d)] = sum_k at[bh,q,k] * v[b,k,h*32+d] ------
__global__ __launch_bounds__(256) void attn_ctx(
    const float* __restrict__ at, const float* __restrict__ vb,
    float* __restrict__ out) {
  __shared__ float at_s[200][33];
  __shared__ float v_s[32][33];
  const int bh = blockIdx.x;
  const int b = bh >> 3, h = bh & 7;
  const float* A = at + (long)bh * N_ * N_;
  const float* V = vb + (long)b * N_ * 256 + h * 32;
  float* O = out + (long)b * N_ * 256 + h * 32;
  const int tid = threadIdx.x;
  const int d = tid & 31, qg = tid >> 5;
  float acc[25];
#pragma unroll
  for (int s = 0; s < 25; ++s) acc[s] = 0.f;
  for (int k0 = 0; k0 < N_; k0 += 32) {
    const int kw = N_ - k0 < 32 ? N_ - k0 : 32;
    for (int e = tid; e < 200 * 32; e += 256) {
      const int q = e >> 5, kk = e & 31;
      at_s[q][kk] = (kk < kw) ? A[(long)q * N_ + k0 + kk] : 0.f;
    }
    for (int e = tid; e < 32 * 32; e += 256) {
      const int kk = e >> 5, dd = e & 31;
      v_s[kk][dd] = (kk < kw) ? V[(long)(k0 + kk) * 256 + dd] : 0.f;
    }
    __syncthreads();
#pragma unroll
    for (int kk = 0; kk < 32; ++kk) {
      const float vv = v_s[kk][d];
#pragma unroll
      for (int s = 0; s < 25; ++s) acc[s] += at_s[qg + 8 * s][kk] * vv;
    }
    __syncthreads();
  }
#pragma unroll
  for (int s = 0; s < 25; ++s) O[(long)(qg + 8 * s) * 256 + d] = acc[s];
}

// ---------------- LSTM ----------------
__global__ __launch_bounds__(256) void lstm_gates(
    const float* __restrict__ di, const float* __restrict__ dh,
    const float* __restrict__ Wih, const float* __restrict__ Whh,
    const float* __restrict__ bias, float* __restrict__ gates) {
  const int idx = blockIdx.x * 256 + threadIdx.x;  // 0..65535
  const int b = idx >> 10, n = idx & 1023;
  const float* w1 = Wih + (long)n * 256;
  const float* w2 = Whh + (long)n * 256;
  const float* x1 = di + b * 256;
  const float* x2 = dh + b * 256;
  float s = bias[n];
  for (int k = 0; k < 256; ++k) s += x1[k] * w1[k] + x2[k] * w2[k];
  gates[idx] = s;
}

__global__ __launch_bounds__(256) void lstm_ew(
    const float* __restrict__ gates, const float* __restrict__ dc,
    float* __restrict__ h_out, float* __restrict__ c_out) {
  const int idx = blockIdx.x * 256 + threadIdx.x;  // 0..16383
  const int b = idx >> 8, d = idx & 255;
  const float ig = sigmoidf_(gates[b * 1024 + d]);
  const float fg = sigmoidf_(gates[b * 1024 + 256 + d]);
  const float gg = tanhf(gates[b * 1024 + 512 + d]);
  const float og = sigmoidf_(gates[b * 1024 + 768 + d]);
  const float c = fg * dc[idx] + ig * gg;
  c_out[idx] = c;
  h_out[idx] = og * tanhf(c);
}

__global__ __launch_bounds__(256) void hq_gemm(
    const float* __restrict__ h, const float* __restrict__ Wq, float* __restrict__ hq) {
  const int b = blockIdx.x;
  const int n = threadIdx.x;
  float s = 0.f;
  for (int k = 0; k < 256; ++k) s += h[b * 256 + k] * Wq[k * 256 + n];
  hq[b * 256 + n] = s;
}

// ---------------- pointer: u[b,n] = sum_d tanh(pref + hq) * v[d] ----------------
__global__ __launch_bounds__(64) void ptr_u(
    const float* __restrict__ pref, const float* __restrict__ hq,
    const float* __restrict__ pv, float* __restrict__ u) {
  const int row = blockIdx.x;  // b*N + n
  const int b = row / N_;
  const int lane = threadIdx.x;
  float s = 0.f;
  for (int d = lane; d < 256; d += 64)
    s += tanhf(pref[(long)row * 256 + d] + hq[b * 256 + d]) * pv[d];
  s = wave_sum64(s);
  if (lane == 0) u[row] = s;
}

__global__ __launch_bounds__(256) void policy_softmax(
    const float* __restrict__ u, const int* __restrict__ mask, float* __restrict__ pol) {
  const int b = blockIdx.x, t = threadIdx.x;
  float val = -1e30f;
  if (t < N_) val = (mask[b * N_ + t] > 0) ? u[b * N_ + t] : -1e9f;
  float m = val;
#pragma unroll
  for (int off = 32; off; off >>= 1) m = fmaxf(m, __shfl_xor(m, off));
  __shared__ float sh[8];
  const int wid = t >> 6, lane = t & 63;
  if (lane == 0) sh[wid] = m;
  __syncthreads();
  m = fmaxf(fmaxf(sh[0], sh[1]), fmaxf(sh[2], sh[3]));
  const float e = (t < N_) ? __expf(val - m) : 0.f;
  float s = e;
#pragma unroll
  for (int off = 32; off; off >>= 1) s += __shfl_xor(s, off);
  __syncthreads();
  if (lane == 0) sh[4 + wid] = s;
  __syncthreads();
  const float S = sh[4] + sh[5] + sh[6] + sh[7];
  if (t < N_) pol[b * N_ + t] = e / S;
}

extern "C" void kernel_launch(void* const* d_in, const int* in_sizes, int n_in,
                              void* d_out, int out_size, void* d_ws, size_t ws_size,
                              hipStream_t stream) {
  const float* enc_inputs = (const float*)d_in[0];
  const float* dec_input = (const float*)d_in[1];
  const float* dec_h = (const float*)d_in[2];
  const float* dec_c = (const float*)d_in[3];
  const float* gat_W = (const float*)d_in[4];
  const float* gat_att_src = (const float*)d_in[5];
  const float* gat_att_dst = (const float*)d_in[6];
  const float* gat_bias = (const float*)d_in[7];
  const float* gat_ln = (const float*)d_in[8];
  const float* enc_attn_W = (const float*)d_in[9];
  const float* enc_attn_b = (const float*)d_in[10];
  const float* enc_ln1 = (const float*)d_in[11];
  const float* enc_ffn_W1 = (const float*)d_in[12];
  const float* enc_ffn_b1 = (const float*)d_in[13];
  const float* enc_ffn_W2 = (const float*)d_in[14];
  const float* enc_ffn_b2 = (const float*)d_in[15];
  const float* enc_ln2 = (const float*)d_in[16];
  const float* lstm_Wih = (const float*)d_in[17];
  const float* lstm_Whh = (const float*)d_in[18];
  const float* lstm_b = (const float*)d_in[19];
  const float* ptr_Wref = (const float*)d_in[20];
  const float* ptr_Wq = (const float*)d_in[21];
  const float* ptr_v = (const float*)d_in[22];
  const int* adj = (const int*)d_in[23];
  const int* mask = (const int*)d_in[24];

  float* out = (float*)d_out;
  float* policy = out;                 // 12800
  float* h_out = out + 12800;          // 16384
  float* c_out = out + 12800 + 16384;  // 16384
  float* emb = out + 12800 + 16384 + 16384;  // 3,276,800

  // workspace layout (floats)
  float* ws = (float*)d_ws;
  float* xp = ws;                       // 26,214,400  [B,N,8*256]
  float* attn = xp + 26214400;          // 20,480,000  [B*8,N,N]
  float* xbuf = attn + 20480000;        // 3,276,800
  float* tmp = xbuf + 3276800;          // 3,276,800
  float* qb = tmp + 3276800;            // 3,276,800
  float* kb = qb + 3276800;             // 3,276,800
  float* vb = kb + 3276800;             // 3,276,800
  float* asrc = vb + 3276800;           // 102,400
  float* adst = asrc + 102400;          // 102,400
  float* gates = adst + 102400;         // 65,536
  float* hq = gates + 65536;            // 16,384
  float* ubuf = hq + 16384;             // 12,800
  const size_t need = (size_t)(63377920) * 4;
  if (ws_size < need) fprintf(stderr, "kernel_launch: ws too small (%zu < %zu)\n", ws_size, need);

  // ---------------- GAT stack ----------------
  for (int g = 0; g < G_; ++g) {
    const float* xin = (g == 0) ? enc_inputs : xbuf;
    gemm_f32<0, false, false><<<dim3(BN_ / 64, 2048 / 64), 256, 0, stream>>>(
        xin, gat_W + (long)g * H_ * (NH_ * H_), nullptr, nullptr, xp,
        BN_, NH_ * H_, H_, H_, NH_ * H_, NH_ * H_);
    gat_attvec<<<BN_, 256, 0, stream>>>(xp, gat_att_src + g * NH_ * H_,
                                        gat_att_dst + g * NH_ * H_, asrc, adst);
    gat_attn_softmax<<<BN_ * NH_, 64, 0, stream>>>(asrc, adst, adj, attn);
    gat_msg<<<dim3((N_ + 63) / 64, H_ / 64, B_), 256, 0, stream>>>(
        attn, xp, gat_bias + g * H_, xin, xbuf);
  }
  ln_kernel<1><<<BN_, 256, 0, stream>>>(enc_inputs, xbuf, gat_ln, emb);

  // ---------------- Transformer encoder ----------------
  for (int l = 0; l < L_; ++l) {
    const float* W = enc_attn_W + (long)l * 4 * 65536;
    const float* bW = enc_attn_b + l * 4 * 256;
    gemm_f32<0, true, false><<<dim3(200, 4), 256, 0, stream>>>(
        emb, W, bW, nullptr, qb, BN_, 256, 256, 256, 256, 256);
    gemm_f32<0, true, false><<<dim3(200, 4), 256, 0, stream>>>(
        emb, W + 65536, bW + 256, nullptr, kb, BN_, 256, 256, 256, 256, 256);
    gemm_f32<0, true, false><<<dim3(200, 4), 256, 0, stream>>>(
        emb, W + 131072, bW + 512, nullptr, vb, BN_, 256, 256, 256, 256, 256);
    attn_score_softmax<<<B_ * NH_ * N_, 64, 0, stream>>>(qb, kb, adj, attn);
    attn_ctx<<<B_ * NH_, 256, 0, stream>>>(attn, vb, xbuf);
    gemm_f32<0, true, true><<<dim3(200, 4), 256, 0, stream>>>(
        xbuf, W + 3 * 65536, bW + 768, emb, tmp, BN_, 256, 256, 256, 256, 256);
    ln_kernel<0><<<BN_, 256, 0, stream>>>(tmp, nullptr, enc_ln1 + l * 512, emb);
    gemm_f32<1, true, false><<<dim3(200, 8), 256, 0, stream>>>(
        emb, enc_ffn_W1 + (long)l * 131072, enc_ffn_b1 + l * 512, nullptr, xp,
        BN_, 512, 256, 256, 512, 512);
    gemm_f32<0, true, true><<<dim3(200, 4), 256, 0, stream>>>(
        xp, enc_ffn_W2 + (long)l * 131072, enc_ffn_b2 + l * 256, emb, tmp,
        BN_, 256, 512, 512, 256, 256);
    ln_kernel<0><<<BN_, 256, 0, stream>>>(tmp, nullptr, enc_ln2 + l * 512, emb);
  }

  // ---------------- LSTM cell + pointer ----------------
  lstm_gates<<<256, 256, 0, stream>>>(dec_input, dec_h, lstm_Wih, lstm_Whh, lstm_b, gates);
  lstm_ew<<<64, 256, 0, stream>>>(gates, dec_c, h_out, c_out);
  hq_gemm<<<64, 256, 0, stream>>>(h_out, ptr_Wq, hq);
  gemm_f32<0, false, false><<<dim3(200, 4), 256, 0, stream>>>(
      emb, ptr_Wref, nullptr, nullptr, qb, BN_, 256, 256, 256, 256, 256);
  ptr_u<<<BN_, 64, 0, stream>>>(qb, hq, ptr_v, ubuf);
  policy_softmax<<<B_, 256, 0, stream>>>(ubuf, mask, policy);
}

// Round 3
// 2551.334 us; speedup vs baseline: 1.7434x; 1.7434x over previous
//
#include <hip/hip_runtime.h>
#include <cstdio>
#include <math.h>

static constexpr int B_ = 64, N_ = 200, H_ = 256, NH_ = 8, G_ = 2, L_ = 3, F_ = 512;
static constexpr int BN_ = B_ * N_;  // 12800

typedef unsigned short u16;
typedef __attribute__((ext_vector_type(8))) short short8;
typedef __attribute__((ext_vector_type(4))) float f32x4;

#define LDSP(p) ((__attribute__((address_space(3))) unsigned int*)(p))
#define GLBP(p) ((const __attribute__((address_space(1))) unsigned int*)(p))

__device__ __forceinline__ float wave_sum64(float v) {
#pragma unroll
  for (int off = 32; off; off >>= 1) v += __shfl_xor(v, off);
  return v;
}
__device__ __forceinline__ float wave_max64(float v) {
#pragma unroll
  for (int off = 32; off; off >>= 1) v = fmaxf(v, __shfl_xor(v, off));
  return v;
}
__device__ __forceinline__ float sigmoidf_(float x) { return 1.f / (1.f + __expf(-x)); }
__device__ __forceinline__ u16 f2bf(float x) {  // RNE f32->bf16
  unsigned u = __float_as_uint(x);
  return (u16)((u + 0x7FFFu + ((u >> 16) & 1u)) >> 16);
}

// ================= bf16 MFMA GEMM =================
// C[M][Nn] = act(A @ Bt^T + bias + res). A: bf16 [M][K]; Bt: bf16 [Nn][K].
// Tile 128x128, BK=64, 4 waves (2x2 of 64x64). K % 64 == 0, M % 128 == 0, Nn % 128 == 0.
template <int ACT, bool HAS_BIAS, bool HAS_RES, bool OUT_BF>
__global__ __launch_bounds__(256) void gemm_bf16(
    const u16* __restrict__ A, const u16* __restrict__ Bt,
    const float* __restrict__ bias, const float* __restrict__ res,
    float* __restrict__ Cf, u16* __restrict__ Cb, int M, int Nn, int K) {
  __shared__ u16 As[128 * 64];
  __shared__ u16 Bs[128 * 64];
  char* asB = (char*)As;
  char* bsB = (char*)Bs;
  const int tid = threadIdx.x;
  const int m0 = blockIdx.x * 128, n0 = blockIdx.y * 128;
  const int lane = tid & 63;
  const int wid = tid >> 6;
  const int wr = (wid >> 1) * 64, wc = (wid & 1) * 64;
  const int Kb = K * 2;
  const char* Ab = (const char*)A + (size_t)m0 * Kb;
  const char* Bb = (const char*)Bt + (size_t)n0 * Kb;
  f32x4 acc[4][4];
#pragma unroll
  for (int i = 0; i < 4; ++i)
#pragma unroll
    for (int j = 0; j < 4; ++j)
#pragma unroll
      for (int r = 0; r < 4; ++r) acc[i][j][r] = 0.f;

  for (int k0 = 0; k0 < K; k0 += 64) {
    if (k0) __syncthreads();
#pragma unroll
    for (int it = 0; it < 4; ++it) {
      const unsigned o = (unsigned)(it * 256 + tid) * 16;  // linear LDS byte offset
      const int row = o >> 7;
      const unsigned bc = (o & 127u) ^ (unsigned)((row & 7) << 4);  // inverse-swizzled src col
      const unsigned wb = o & ~1023u;  // wave-uniform LDS base
      __builtin_amdgcn_global_load_lds(GLBP(Ab + (size_t)row * Kb + k0 * 2 + bc),
                                       LDSP(asB + wb), 16, 0, 0);
      __builtin_amdgcn_global_load_lds(GLBP(Bb + (size_t)row * Kb + k0 * 2 + bc),
                                       LDSP(bsB + wb), 16, 0, 0);
    }
    __syncthreads();
#pragma unroll
    for (int kk = 0; kk < 2; ++kk) {
      short8 aF[4], bF[4];
#pragma unroll
      for (int i = 0; i < 4; ++i) {
        const int ar = wr + i * 16 + (lane & 15);
        const unsigned ac = (unsigned)(kk * 64 + (lane >> 4) * 16) ^ (unsigned)((ar & 7) << 4);
        aF[i] = *(const short8*)(asB + ar * 128 + ac);
        const int br = wc + i * 16 + (lane & 15);
        const unsigned bc2 = (unsigned)(kk * 64 + (lane >> 4) * 16) ^ (unsigned)((br & 7) << 4);
        bF[i] = *(const short8*)(bsB + br * 128 + bc2);
      }
#pragma unroll
      for (int i = 0; i < 4; ++i)
#pragma unroll
        for (int j = 0; j < 4; ++j)
          acc[i][j] = __builtin_amdgcn_mfma_f32_16x16x32_bf16(aF[i], bF[j], acc[i][j], 0, 0, 0);
    }
  }
  // epilogue: C/D layout col=lane&15, row=(lane>>4)*4+reg  [m89]
#pragma unroll
  for (int i = 0; i < 4; ++i) {
    const int gm0 = m0 + wr + i * 16 + (lane >> 4) * 4;
#pragma unroll
    for (int j = 0; j < 4; ++j) {
      const int gn = n0 + wc + j * 16 + (lane & 15);
      const float bv = HAS_BIAS ? bias[gn] : 0.f;
#pragma unroll
      for (int r = 0; r < 4; ++r) {
        const int gm = gm0 + r;
        float v = acc[i][j][r] + bv;
        if (HAS_RES) v += res[(size_t)gm * Nn + gn];
        if (ACT == 1) v = fmaxf(v, 0.f);
        if (OUT_BF)
          Cb[(size_t)gm * Nn + gn] = f2bf(v);
        else
          Cf[(size_t)gm * Nn + gn] = v;
      }
    }
  }
}

// ================= weight prep: transpose f32 [R][C] -> bf16 [C][R] =================
__device__ const int PREP_TBL[21][6] = {
    // srcSel, srcOff, dstSel, dstOff, R, C
    {0, 0, 0, 0, 256, 2048},
    {0, 524288, 0, 524288, 256, 2048},
    {1, 0 * 65536, 1, 0, 256, 256},      {1, 1 * 65536, 1, 65536, 256, 256},
    {1, 2 * 65536, 1, 131072, 256, 256}, {1, 4 * 65536, 1, 196608, 256, 256},
    {1, 5 * 65536, 1, 262144, 256, 256}, {1, 6 * 65536, 1, 327680, 256, 256},
    {1, 8 * 65536, 1, 393216, 256, 256}, {1, 9 * 65536, 1, 458752, 256, 256},
    {1, 10 * 65536, 1, 524288, 256, 256},
    {1, 3 * 65536, 2, 0, 256, 256},      {1, 7 * 65536, 2, 65536, 256, 256},
    {1, 11 * 65536, 2, 131072, 256, 256},
    {2, 0, 3, 0, 256, 512}, {2, 131072, 3, 131072, 256, 512}, {2, 262144, 3, 262144, 256, 512},
    {3, 0, 4, 0, 512, 256}, {3, 131072, 4, 131072, 512, 256}, {3, 262144, 4, 262144, 512, 256},
    {4, 0, 5, 0, 256, 256},
};

__global__ __launch_bounds__(256) void prep_weights(
    const float* __restrict__ gat_W, const float* __restrict__ attn_W,
    const float* __restrict__ W1, const float* __restrict__ W2,
    const float* __restrict__ Wref, u16* __restrict__ gatWT, u16* __restrict__ WqkvT,
    u16* __restrict__ WoT, u16* __restrict__ W1T, u16* __restrict__ W2T,
    u16* __restrict__ WrefT) {
  const int mi = blockIdx.y;
  const int R = PREP_TBL[mi][4], C = PREP_TBL[mi][5];
  const int tc = C / 32;
  const int tiles = (R / 32) * tc;
  if ((int)blockIdx.x >= tiles) return;
  const int sel = PREP_TBL[mi][0], dsel = PREP_TBL[mi][2];
  const float* sp = (sel == 0) ? gat_W : (sel == 1) ? attn_W : (sel == 2) ? W1 : (sel == 3) ? W2 : Wref;
  u16* dp = (dsel == 0) ? gatWT : (dsel == 1) ? WqkvT : (dsel == 2) ? WoT : (dsel == 3) ? W1T
            : (dsel == 4) ? W2T : WrefT;
  sp += PREP_TBL[mi][1];
  dp += PREP_TBL[mi][3];
  const int r0 = (blockIdx.x / tc) * 32, c0 = (blockIdx.x % tc) * 32;
  __shared__ float s[32][33];
  const int tx = threadIdx.x & 31, ty = threadIdx.x >> 5;
#pragma unroll
  for (int u = 0; u < 4; ++u) s[ty + 8 * u][tx] = sp[(size_t)(r0 + ty + 8 * u) * C + c0 + tx];
  __syncthreads();
#pragma unroll
  for (int u = 0; u < 4; ++u)
    dp[(size_t)(c0 + ty + 8 * u) * R + r0 + tx] = f2bf(s[tx][ty + 8 * u]);
}

__global__ __launch_bounds__(256) void cast_bf16(const float* __restrict__ in,
                                                 u16* __restrict__ out, int n4) {
  const int i = blockIdx.x * 256 + threadIdx.x;
  if (i >= n4) return;
  const float4 v = ((const float4*)in)[i];
  ushort4 o;
  o.x = f2bf(v.x); o.y = f2bf(v.y); o.z = f2bf(v.z); o.w = f2bf(v.w);
  ((ushort4*)out)[i] = o;
}

// ================= GAT pieces (f32 path) =================
__global__ __launch_bounds__(256) void gat_attvec(
    const float* __restrict__ xp, const float* __restrict__ att_src,
    const float* __restrict__ att_dst, float* __restrict__ a_src,
    float* __restrict__ a_dst) {
  const int bn = blockIdx.x;
  const int t = threadIdx.x;
  const int h = t >> 5, s = t & 31;
  const float* xr = xp + (long)bn * 2048 + h * 256 + s * 8;
  const float* vs = att_src + h * 256 + s * 8;
  const float* vd = att_dst + h * 256 + s * 8;
  float ps = 0.f, pd = 0.f;
#pragma unroll
  for (int u = 0; u < 8; ++u) {
    const float x = xr[u];
    ps += x * vs[u];
    pd += x * vd[u];
  }
#pragma unroll
  for (int off = 16; off; off >>= 1) {
    ps += __shfl_xor(ps, off);
    pd += __shfl_xor(pd, off);
  }
  if (s == 0) {
    a_src[bn * 8 + h] = ps;
    a_dst[bn * 8 + h] = pd;
  }
}

__global__ __launch_bounds__(64) void gat_attn_softmax(
    const float* __restrict__ a_src, const float* __restrict__ a_dst,
    const int* __restrict__ adj, float* __restrict__ attn) {
  const int id = blockIdx.x;
  const int h = id & 7;
  const int bj = id >> 3;
  const int j = bj % N_, b = bj / N_;
  const float ad = a_dst[bj * 8 + h];
  const int lane = threadIdx.x;
  float vals[4];
  float mx = -1e30f;
#pragma unroll
  for (int r = 0; r < 4; ++r) {
    const int i = lane + r * 64;
    float v = -1e30f;
    if (i < N_) {
      float x = ad + a_src[(b * N_ + i) * 8 + h];
      x = x > 0.f ? x : 0.2f * x;
      const bool ok = (i == j) || (adj[(long)b * N_ * N_ + (long)i * N_ + j] > 0);
      v = ok ? x : -1e9f;
    }
    vals[r] = v;
    mx = fmaxf(mx, v);
  }
  mx = wave_max64(mx);
  float sum = 0.f;
#pragma unroll
  for (int r = 0; r < 4; ++r) {
    const int i = lane + r * 64;
    if (i < N_) {
      const float e = __expf(vals[r] - mx);
      vals[r] = e;
      sum += e;
    }
  }
  sum = wave_sum64(sum);
  const float inv = 1.f / sum;
  float* row = attn + ((long)(b * 8 + h) * N_ + j) * N_;
#pragma unroll
  for (int r = 0; r < 4; ++r) {
    const int i = lane + r * 64;
    if (i < N_) row[i] = vals[r] * inv;
  }
}

__global__ __launch_bounds__(256) void gat_msg(
    const float* __restrict__ attn, const float* __restrict__ xp,
    const float* __restrict__ bias, const float* __restrict__ xin,
    float* __restrict__ xout) {
  __shared__ float As[16][65];
  __shared__ float Bs[16][65];
  const int j0 = blockIdx.x * 64;
  const int d0 = blockIdx.y * 64;
  const int b = blockIdx.z;
  const int tid = threadIdx.x;
  const int tx = tid & 15, ty = tid >> 4;
  float acc[4][4] = {};
  for (int h = 0; h < 8; ++h) {
    const float* Ab = attn + (long)(b * 8 + h) * N_ * N_;
    const float* Bb = xp + (long)b * N_ * 2048 + h * 256;
    for (int k0 = 0; k0 < N_; k0 += 16) {
      {
        const int e = tid * 4;
        const int row = e >> 4, kk = e & 15;
        const int gj = j0 + row;
#pragma unroll
        for (int u = 0; u < 4; ++u) {
          const int gk = k0 + kk + u;
          As[kk + u][row] = (gj < N_ && gk < N_) ? Ab[(long)gj * N_ + gk] : 0.f;
        }
      }
      {
        const int e = tid * 4;
        const int kk = e >> 6, col = e & 63;
        const int gk = k0 + kk;
#pragma unroll
        for (int u = 0; u < 4; ++u)
          Bs[kk][col + u] = (gk < N_) ? Bb[(long)gk * 2048 + d0 + col + u] : 0.f;
      }
      __syncthreads();
#pragma unroll
      for (int kk = 0; kk < 16; ++kk) {
        float a[4], bv[4];
#pragma unroll
        for (int i = 0; i < 4; ++i) a[i] = As[kk][ty * 4 + i];
#pragma unroll
        for (int j = 0; j < 4; ++j) bv[j] = Bs[kk][tx * 4 + j];
#pragma unroll
        for (int i = 0; i < 4; ++i)
#pragma unroll
          for (int j = 0; j < 4; ++j) acc[i][j] += a[i] * bv[j];
      }
      __syncthreads();
    }
  }
#pragma unroll
  for (int i = 0; i < 4; ++i) {
    const int gj = j0 + ty * 4 + i;
    if (gj >= N_) continue;
#pragma unroll
    for (int j = 0; j < 4; ++j) {
      const int gd = d0 + tx * 4 + j;
      const float m = acc[i][j] * 0.125f + bias[gd];
      const long o = (long)(b * N_ + gj) * 256 + gd;
      xout[o] = xin[o] + fmaxf(m, 0.f);
    }
  }
}

// ================= LayerNorm (dual f32 + bf16 out) =================
template <int PRE>
__global__ __launch_bounds__(256) void ln_kernel(
    const float* __restrict__ in1, const float* __restrict__ in2,
    const float* __restrict__ sb, float* __restrict__ out, u16* __restrict__ outB) {
  const int row = blockIdx.x, t = threadIdx.x;
  const long o = (long)row * 256 + t;
  const float v = PRE ? (in1[o] + fmaxf(in2[o], 0.f)) : in1[o];
  float s = v, q = v * v;
#pragma unroll
  for (int off = 32; off; off >>= 1) {
    s += __shfl_xor(s, off);
    q += __shfl_xor(q, off);
  }
  __shared__ float sh[8];
  const int wid = t >> 6, lane = t & 63;
  if (lane == 0) {
    sh[wid] = s;
    sh[4 + wid] = q;
  }
  __syncthreads();
  const float S = sh[0] + sh[1] + sh[2] + sh[3];
  const float Q = sh[4] + sh[5] + sh[6] + sh[7];
  const float mean = S * (1.f / 256.f);
  const float var = Q * (1.f / 256.f) - mean * mean;
  const float r = rsqrtf(var + 1e-5f);
  const float y = (v - mean) * r * sb[t] + sb[256 + t];
  out[o] = y;
  outB[o] = f2bf(y);
}

// ================= encoder attention (f32 path; qkv fused [BN][768]) =================
__global__ __launch_bounds__(64) void attn_score_softmax(
    const float* __restrict__ qkv, const int* __restrict__ adj, float* __restrict__ at) {
  const int id = blockIdx.x;  // (b*8+h)*N + qi
  const int qi = id % N_;
  const int bh = id / N_;
  const int b = bh >> 3, h = bh & 7;
  __shared__ float qs[32];
  const int lane = threadIdx.x;
  if (lane < 32) qs[lane] = qkv[(long)(b * N_ + qi) * 768 + h * 32 + lane];
  __syncthreads();
  const int* arow = adj + (long)b * N_ * N_ + (long)qi * N_;
  float vals[4];
  float mx = -1e30f;
#pragma unroll
  for (int r = 0; r < 4; ++r) {
    const int ki = lane + r * 64;
    float v = -1e30f;
    if (ki < N_) {
      if (arow[ki] > 0) {
        const float* kv = qkv + (long)(b * N_ + ki) * 768 + 256 + h * 32;
        float dot = 0.f;
#pragma unroll
        for (int d = 0; d < 32; ++d) dot += qs[d] * kv[d];
        v = dot * 0.17677669529663687f;
      } else {
        v = -1e9f;
      }
    }
    vals[r] = v;
    mx = fmaxf(mx, v);
  }
  mx = wave_max64(mx);
  float sum = 0.f;
#pragma unroll
  for (int r = 0; r < 4; ++r) {
    const int ki = lane + r * 64;
    if (ki < N_) {
      const float e = __expf(vals[r] - mx);
      vals[r] = e;
      sum += e;
    }
  }
  sum = wave_sum64(sum);
  const float inv = 1.f / sum;
  float* row = at + ((long)bh * N_ + qi) * N_;
#pragma unroll
  for (int r = 0; r < 4; ++r) {
    const int ki = lane + r * 64;
    if (ki < N_) row[ki] = vals[r] * inv;
  }
}

__global__ __launch_bounds__(256) void attn_ctx(
    const float* __restrict__ at, const float* __restrict__ qkv, u16* __restrict__ outB) {
  __shared__ float at_s[200][33];
  __shared__ float v_s[32][33];
  const int bh = blockIdx.x;
  const int b = bh >> 3, h = bh & 7;
  const float* A = at + (long)bh * N_ * N_;
  const float* V = qkv + (long)b * N_ * 768 + 512 + h * 32;
  u16* O = outB + (long)b * N_ * 256 + h * 32;
  const int tid = threadIdx.x;
  const int d = tid & 31, qg = tid >> 5;
  float acc[25];
#pragma unroll
  for (int s = 0; s < 25; ++s) acc[s] = 0.f;
  for (int k0 = 0; k0 < N_; k0 += 32) {
    const int kw = N_ - k0 < 32 ? N_ - k0 : 32;
    for (int e = tid; e < 200 * 32; e += 256) {
      const int q = e >> 5, kk = e & 31;
      at_s[q][kk] = (kk < kw) ? A[(long)q * N_ + k0 + kk] : 0.f;
    }
    for (int e = tid; e < 32 * 32; e += 256) {
      const int kk = e >> 5, dd = e & 31;
      v_s[kk][dd] = (kk < kw) ? V[(long)(k0 + kk) * 768 + dd] : 0.f;
    }
    __syncthreads();
#pragma unroll
    for (int kk = 0; kk < 32; ++kk) {
      const float vv = v_s[kk][d];
#pragma unroll
      for (int s = 0; s < 25; ++s) acc[s] += at_s[qg + 8 * s][kk] * vv;
    }
    __syncthreads();
  }
#pragma unroll
  for (int s = 0; s < 25; ++s) O[(long)(qg + 8 * s) * 256 + d] = f2bf(acc[s]);
}

// ================= LSTM + pointer =================
__global__ __launch_bounds__(256) void lstm_gates(
    const float* __restrict__ di, const float* __restrict__ dh,
    const float* __restrict__ Wih, const float* __restrict__ Whh,
    const float* __restrict__ bias, float* __restrict__ gates) {
  const int idx = blockIdx.x * 256 + threadIdx.x;
  const int b = idx >> 10, n = idx & 1023;
  const float* w1 = Wih + (long)n * 256;
  const float* w2 = Whh + (long)n * 256;
  const float* x1 = di + b * 256;
  const float* x2 = dh + b * 256;
  float s = bias[n];
  for (int k = 0; k < 256; ++k) s += x1[k] * w1[k] + x2[k] * w2[k];
  gates[idx] = s;
}

__global__ __launch_bounds__(256) void lstm_ew(
    const float* __restrict__ gates, const float* __restrict__ dc,
    float* __restrict__ h_out, float* __restrict__ c_out) {
  const int idx = blockIdx.x * 256 + threadIdx.x;
  const int b = idx >> 8, d = idx & 255;
  const float ig = sigmoidf_(gates[b * 1024 + d]);
  const float fg = sigmoidf_(gates[b * 1024 + 256 + d]);
  const float gg = tanhf(gates[b * 1024 + 512 + d]);
  const float og = sigmoidf_(gates[b * 1024 + 768 + d]);
  const float c = fg * dc[idx] + ig * gg;
  c_out[idx] = c;
  h_out[idx] = og * tanhf(c);
}

__global__ __launch_bounds__(256) void hq_gemm(
    const float* __restrict__ h, const float* __restrict__ Wq, float* __restrict__ hq) {
  const int b = blockIdx.x;
  const int n = threadIdx.x;
  float s = 0.f;
  for (int k = 0; k < 256; ++k) s += h[b * 256 + k] * Wq[k * 256 + n];
  hq[b * 256 + n] = s;
}

__global__ __launch_bounds__(64) void ptr_u(
    const float* __restrict__ pref, const float* __restrict__ hq,
    const float* __restrict__ pv, float* __restrict__ u) {
  const int row = blockIdx.x;
  const int b = row / N_;
  const int lane = threadIdx.x;
  float s = 0.f;
  for (int d = lane; d < 256; d += 64)
    s += tanhf(pref[(long)row * 256 + d] + hq[b * 256 + d]) * pv[d];
  s = wave_sum64(s);
  if (lane == 0) u[row] = s;
}

__global__ __launch_bounds__(256) void policy_softmax(
    const float* __restrict__ u, const int* __restrict__ mask, float* __restrict__ pol) {
  const int b = blockIdx.x, t = threadIdx.x;
  float val = -1e30f;
  if (t < N_) val = (mask[b * N_ + t] > 0) ? u[b * N_ + t] : -1e9f;
  float m = val;
#pragma unroll
  for (int off = 32; off; off >>= 1) m = fmaxf(m, __shfl_xor(m, off));
  __shared__ float sh[8];
  const int wid = t >> 6, lane = t & 63;
  if (lane == 0) sh[wid] = m;
  __syncthreads();
  m = fmaxf(fmaxf(sh[0], sh[1]), fmaxf(sh[2], sh[3]));
  const float e = (t < N_) ? __expf(val - m) : 0.f;
  float s = e;
#pragma unroll
  for (int off = 32; off; off >>= 1) s += __shfl_xor(s, off);
  __syncthreads();
  if (lane == 0) sh[4 + wid] = s;
  __syncthreads();
  const float S = sh[4] + sh[5] + sh[6] + sh[7];
  if (t < N_) pol[b * N_ + t] = e / S;
}

extern "C" void kernel_launch(void* const* d_in, const int* in_sizes, int n_in,
                              void* d_out, int out_size, void* d_ws, size_t ws_size,
                              hipStream_t stream) {
  const float* enc_inputs = (const float*)d_in[0];
  const float* dec_input = (const float*)d_in[1];
  const float* dec_h = (const float*)d_in[2];
  const float* dec_c = (const float*)d_in[3];
  const float* gat_W = (const float*)d_in[4];
  const float* gat_att_src = (const float*)d_in[5];
  const float* gat_att_dst = (const float*)d_in[6];
  const float* gat_bias = (const float*)d_in[7];
  const float* gat_ln = (const float*)d_in[8];
  const float* enc_attn_W = (const float*)d_in[9];
  const float* enc_attn_b = (const float*)d_in[10];
  const float* enc_ln1 = (const float*)d_in[11];
  const float* enc_ffn_W1 = (const float*)d_in[12];
  const float* enc_ffn_b1 = (const float*)d_in[13];
  const float* enc_ffn_W2 = (const float*)d_in[14];
  const float* enc_ffn_b2 = (const float*)d_in[15];
  const float* enc_ln2 = (const float*)d_in[16];
  const float* lstm_Wih = (const float*)d_in[17];
  const float* lstm_Whh = (const float*)d_in[18];
  const float* lstm_b = (const float*)d_in[19];
  const float* ptr_Wref = (const float*)d_in[20];
  const float* ptr_Wq = (const float*)d_in[21];
  const float* ptr_v = (const float*)d_in[22];
  const int* adj = (const int*)d_in[23];
  const int* mask = (const int*)d_in[24];

  float* out = (float*)d_out;
  float* policy = out;                       // 12800
  float* h_out = out + 12800;                // 16384
  float* c_out = out + 12800 + 16384;        // 16384
  float* emb = out + 12800 + 16384 + 16384;  // 3,276,800

  // ---- workspace layout (bytes) ----
  char* ws = (char*)d_ws;
  size_t o = 0;
  float* xp = (float*)(ws + o); o += 104857600;      // [B,N,2048] f32; also hosts qkv & pref
  float* attn = (float*)(ws + o); o += 81920000;     // [B*8,N,N] f32; also hosts ffnB
  float* xbuf = (float*)(ws + o); o += 13107200;
  float* tmp = (float*)(ws + o); o += 13107200;
  float* asrc = (float*)(ws + o); o += 409600;
  float* adst = (float*)(ws + o); o += 409600;
  float* gates = (float*)(ws + o); o += 262144;
  float* hq = (float*)(ws + o); o += 65536;
  float* ubuf = (float*)(ws + o); o += 51200;
  u16* encB = (u16*)(ws + o); o += 6553600;
  u16* xbufB = (u16*)(ws + o); o += 6553600;
  u16* embB = (u16*)(ws + o); o += 6553600;
  u16* ctxB = (u16*)(ws + o); o += 6553600;
  u16* gatWT = (u16*)(ws + o); o += 2097152;
  u16* WqkvT = (u16*)(ws + o); o += 1179648;
  u16* WoT = (u16*)(ws + o); o += 393216;
  u16* W1T = (u16*)(ws + o); o += 786432;
  u16* W2T = (u16*)(ws + o); o += 786432;
  u16* WrefT = (u16*)(ws + o); o += 131072;
  if (ws_size < o) fprintf(stderr, "kernel_launch: ws too small (%zu < %zu)\n", ws_size, o);
  float* qkv = xp;    // [BN][768] f32 (encoder phase; xp is dead then)
  float* pref = xp;   // [BN][256] f32 (pointer phase)
  u16* ffnB = (u16*)attn;  // [BN][512] bf16 (FFN phase; attn re-written next layer)

  // ---- weight prep + input cast ----
  prep_weights<<<dim3(512, 21), 256, 0, stream>>>(gat_W, enc_attn_W, enc_ffn_W1, enc_ffn_W2,
                                                  ptr_Wref, gatWT, WqkvT, WoT, W1T, W2T, WrefT);
  cast_bf16<<<3200, 256, 0, stream>>>(enc_inputs, encB, 819200);

  // ---- GAT stack ----
  for (int g = 0; g < G_; ++g) {
    const u16* AinB = (g == 0) ? encB : xbufB;
    const float* xin = (g == 0) ? enc_inputs : xbuf;
    gemm_bf16<0, false, false, false><<<dim3(100, 16), 256, 0, stream>>>(
        AinB, gatWT + (size_t)g * 524288, nullptr, nullptr, xp, nullptr, BN_, 2048, 256);
    gat_attvec<<<BN_, 256, 0, stream>>>(xp, gat_att_src + g * 2048, gat_att_dst + g * 2048,
                                        asrc, adst);
    gat_attn_softmax<<<BN_ * NH_, 64, 0, stream>>>(asrc, adst, adj, attn);
    gat_msg<<<dim3(4, 4, B_), 256, 0, stream>>>(attn, xp, gat_bias + g * H_, xin, xbuf);
    if (g == 0) cast_bf16<<<3200, 256, 0, stream>>>(xbuf, xbufB, 819200);
  }
  ln_kernel<1><<<BN_, 256, 0, stream>>>(enc_inputs, xbuf, gat_ln, emb, embB);

  // ---- Transformer encoder ----
  for (int l = 0; l < L_; ++l) {
    gemm_bf16<0, true, false, false><<<dim3(100, 6), 256, 0, stream>>>(
        embB, WqkvT + (size_t)l * 196608, enc_attn_b + l * 1024, nullptr, qkv, nullptr,
        BN_, 768, 256);
    attn_score_softmax<<<B_ * NH_ * N_, 64, 0, stream>>>(qkv, adj, attn);
    attn_ctx<<<B_ * NH_, 256, 0, stream>>>(attn, qkv, ctxB);
    gemm_bf16<0, true, true, false><<<dim3(100, 2), 256, 0, stream>>>(
        ctxB, WoT + (size_t)l * 65536, enc_attn_b + l * 1024 + 768, emb, tmp, nullptr,
        BN_, 256, 256);
    ln_kernel<0><<<BN_, 256, 0, stream>>>(tmp, nullptr, enc_ln1 + l * 512, emb, embB);
    gemm_bf16<1, true, false, true><<<dim3(100, 4), 256, 0, stream>>>(
        embB, W1T + (size_t)l * 131072, enc_ffn_b1 + l * 512, nullptr, nullptr, ffnB,
        BN_, 512, 256);
    gemm_bf16<0, true, true, false><<<dim3(100, 2), 256, 0, stream>>>(
        ffnB, W2T + (size_t)l * 131072, enc_ffn_b2 + l * 256, emb, tmp, nullptr,
        BN_, 256, 512);
    ln_kernel<0><<<BN_, 256, 0, stream>>>(tmp, nullptr, enc_ln2 + l * 512, emb, embB);
  }

  // ---- LSTM + pointer ----
  lstm_gates<<<256, 256, 0, stream>>>(dec_input, dec_h, lstm_Wih, lstm_Whh, lstm_b, gates);
  lstm_ew<<<64, 256, 0, stream>>>(gates, dec_c, h_out, c_out);
  hq_gemm<<<64, 256, 0, stream>>>(h_out, ptr_Wq, hq);
  gemm_bf16<0, false, false, false><<<dim3(100, 2), 256, 0, stream>>>(
      embB, WrefT, nullptr, nullptr, pref, nullptr, BN_, 256, 256);
  ptr_u<<<BN_, 64, 0, stream>>>(pref, hq, ptr_v, ubuf);
  policy_softmax<<<B_, 256, 0, stream>>>(ubuf, mask, policy);
}

// Round 4
// 1915.865 us; speedup vs baseline: 2.3216x; 1.3317x over previous
//
#include <hip/hip_runtime.h>
#include <cstdio>
#include <math.h>

static constexpr int B_ = 64, N_ = 200, H_ = 256, NH_ = 8, G_ = 2, L_ = 3, F_ = 512;
static constexpr int BN_ = B_ * N_;  // 12800

typedef unsigned short u16;
typedef __attribute__((ext_vector_type(8))) short short8;
typedef __attribute__((ext_vector_type(4))) float f32x4;

#define LDSP(p) ((__attribute__((address_space(3))) unsigned int*)(p))
#define GLBP(p) ((const __attribute__((address_space(1))) unsigned int*)(p))

__device__ __forceinline__ float wave_sum64(float v) {
#pragma unroll
  for (int off = 32; off; off >>= 1) v += __shfl_xor(v, off);
  return v;
}
__device__ __forceinline__ float wave_max64(float v) {
#pragma unroll
  for (int off = 32; off; off >>= 1) v = fmaxf(v, __shfl_xor(v, off));
  return v;
}
__device__ __forceinline__ float sigmoidf_(float x) { return 1.f / (1.f + __expf(-x)); }
__device__ __forceinline__ u16 f2bf(float x) {  // RNE f32->bf16
  unsigned u = __float_as_uint(x);
  return (u16)((u + 0x7FFFu + ((u >> 16) & 1u)) >> 16);
}
__device__ __forceinline__ float bf2f(u16 x) { return __uint_as_float((unsigned)x << 16); }

// ================= bf16 MFMA GEMM =================
// C[M][Nn] = act(A @ Bt^T + bias + res). A: bf16 [M][K]; Bt: bf16 [Nn][K].
// Tile 128x128, BK=64, 4 waves (2x2 of 64x64). K%64==0, M%128==0, Nn%128==0.
template <int ACT, bool HAS_BIAS, bool HAS_RES, bool OUT_BF>
__global__ __launch_bounds__(256) void gemm_bf16(
    const u16* __restrict__ A, const u16* __restrict__ Bt,
    const float* __restrict__ bias, const float* __restrict__ res,
    float* __restrict__ Cf, u16* __restrict__ Cb, int M, int Nn, int K) {
  __shared__ u16 As[128 * 64];
  __shared__ u16 Bs[128 * 64];
  char* asB = (char*)As;
  char* bsB = (char*)Bs;
  const int tid = threadIdx.x;
  const int m0 = blockIdx.x * 128, n0 = blockIdx.y * 128;
  const int lane = tid & 63;
  const int wid = tid >> 6;
  const int wr = (wid >> 1) * 64, wc = (wid & 1) * 64;
  const int Kb = K * 2;
  const char* Ab = (const char*)A + (size_t)m0 * Kb;
  const char* Bb = (const char*)Bt + (size_t)n0 * Kb;
  f32x4 acc[4][4];
#pragma unroll
  for (int i = 0; i < 4; ++i)
#pragma unroll
    for (int j = 0; j < 4; ++j)
#pragma unroll
      for (int r = 0; r < 4; ++r) acc[i][j][r] = 0.f;

  for (int k0 = 0; k0 < K; k0 += 64) {
    if (k0) __syncthreads();
#pragma unroll
    for (int it = 0; it < 4; ++it) {
      const unsigned o = (unsigned)(it * 256 + tid) * 16;  // linear LDS byte offset
      const int row = o >> 7;
      const unsigned bc = (o & 127u) ^ (unsigned)((row & 7) << 4);  // inverse-swizzled src col
      const unsigned wb = o & ~1023u;  // wave-uniform LDS base
      __builtin_amdgcn_global_load_lds(GLBP(Ab + (size_t)row * Kb + k0 * 2 + bc),
                                       LDSP(asB + wb), 16, 0, 0);
      __builtin_amdgcn_global_load_lds(GLBP(Bb + (size_t)row * Kb + k0 * 2 + bc),
                                       LDSP(bsB + wb), 16, 0, 0);
    }
    __syncthreads();
#pragma unroll
    for (int kk = 0; kk < 2; ++kk) {
      short8 aF[4], bF[4];
#pragma unroll
      for (int i = 0; i < 4; ++i) {
        const int ar = wr + i * 16 + (lane & 15);
        const unsigned ac = (unsigned)(kk * 64 + (lane >> 4) * 16) ^ (unsigned)((ar & 7) << 4);
        aF[i] = *(const short8*)(asB + ar * 128 + ac);
        const int br = wc + i * 16 + (lane & 15);
        const unsigned bc2 = (unsigned)(kk * 64 + (lane >> 4) * 16) ^ (unsigned)((br & 7) << 4);
        bF[i] = *(const short8*)(bsB + br * 128 + bc2);
      }
#pragma unroll
      for (int i = 0; i < 4; ++i)
#pragma unroll
        for (int j = 0; j < 4; ++j)
          acc[i][j] = __builtin_amdgcn_mfma_f32_16x16x32_bf16(aF[i], bF[j], acc[i][j], 0, 0, 0);
    }
  }
  // epilogue: C/D layout col=lane&15, row=(lane>>4)*4+reg  [m89]
#pragma unroll
  for (int i = 0; i < 4; ++i) {
    const int gm0 = m0 + wr + i * 16 + (lane >> 4) * 4;
#pragma unroll
    for (int j = 0; j < 4; ++j) {
      const int gn = n0 + wc + j * 16 + (lane & 15);
      const float bv = HAS_BIAS ? bias[gn] : 0.f;
#pragma unroll
      for (int r = 0; r < 4; ++r) {
        const int gm = gm0 + r;
        float v = acc[i][j][r] + bv;
        if (HAS_RES) v += res[(size_t)gm * Nn + gn];
        if (ACT == 1) v = fmaxf(v, 0.f);
        if (OUT_BF)
          Cb[(size_t)gm * Nn + gn] = f2bf(v);
        else
          Cf[(size_t)gm * Nn + gn] = v;
      }
    }
  }
}

// ================= GAT message MFMA =================
// out[b,j,d] = xin[b,j,d] + relu( (1/8) sum_{h,i} attnB[b,h,j,i]*xpT[b,h,d,i] + bias[d] )
// attnB,xpT: bf16 [B*8][256][256] slabs (k-pad zeroed). grid (2,2,B), 256 thr.
__global__ __launch_bounds__(256) void gat_msg_mfma(
    const u16* __restrict__ attnB, const u16* __restrict__ xpT,
    const float* __restrict__ bias, const float* __restrict__ xin,
    float* __restrict__ xout, u16* __restrict__ xoutB) {
  __shared__ u16 As[128 * 64];
  __shared__ u16 Bs[128 * 64];
  char* asB = (char*)As;
  char* bsB = (char*)Bs;
  const int tid = threadIdx.x;
  const int m0 = blockIdx.x * 128, n0 = blockIdx.y * 128;
  const int b = blockIdx.z;
  const int lane = tid & 63, wid = tid >> 6;
  const int wr = (wid >> 1) * 64, wc = (wid & 1) * 64;
  f32x4 acc[4][4];
#pragma unroll
  for (int i = 0; i < 4; ++i)
#pragma unroll
    for (int j = 0; j < 4; ++j)
#pragma unroll
      for (int r = 0; r < 4; ++r) acc[i][j][r] = 0.f;
  const char* baseA = (const char*)attnB + ((size_t)b << 20) + (size_t)m0 * 512;
  const char* baseB = (const char*)xpT + ((size_t)b << 20) + (size_t)n0 * 512;
  for (int t = 0; t < 32; ++t) {
    const size_t hoff = (size_t)(t >> 2) * 131072;  // slab stride per head
    const int k0 = (t & 3) * 64;
    if (t) __syncthreads();
#pragma unroll
    for (int it = 0; it < 4; ++it) {
      const unsigned o = (unsigned)(it * 256 + tid) * 16;
      const int row = o >> 7;
      const unsigned bc = (o & 127u) ^ (unsigned)((row & 7) << 4);
      const unsigned wb = o & ~1023u;
      __builtin_amdgcn_global_load_lds(GLBP(baseA + hoff + (size_t)row * 512 + k0 * 2 + bc),
                                       LDSP(asB + wb), 16, 0, 0);
      __builtin_amdgcn_global_load_lds(GLBP(baseB + hoff + (size_t)row * 512 + k0 * 2 + bc),
                                       LDSP(bsB + wb), 16, 0, 0);
    }
    __syncthreads();
#pragma unroll
    for (int kk = 0; kk < 2; ++kk) {
      short8 aF[4], bF[4];
#pragma unroll
      for (int i = 0; i < 4; ++i) {
        const int ar = wr + i * 16 + (lane & 15);
        const unsigned ac = (unsigned)(kk * 64 + (lane >> 4) * 16) ^ (unsigned)((ar & 7) << 4);
        aF[i] = *(const short8*)(asB + ar * 128 + ac);
        const int br = wc + i * 16 + (lane & 15);
        const unsigned bc2 = (unsigned)(kk * 64 + (lane >> 4) * 16) ^ (unsigned)((br & 7) << 4);
        bF[i] = *(const short8*)(bsB + br * 128 + bc2);
      }
#pragma unroll
      for (int i = 0; i < 4; ++i)
#pragma unroll
        for (int j = 0; j < 4; ++j)
          acc[i][j] = __builtin_amdgcn_mfma_f32_16x16x32_bf16(aF[i], bF[j], acc[i][j], 0, 0, 0);
    }
  }
#pragma unroll
  for (int i = 0; i < 4; ++i) {
    const int gm0 = m0 + wr + i * 16 + (lane >> 4) * 4;
#pragma unroll
    for (int j = 0; j < 4; ++j) {
      const int gn = n0 + wc + j * 16 + (lane & 15);
      const float bv = bias[gn];
#pragma unroll
      for (int r = 0; r < 4; ++r) {
        const int gm = gm0 + r;
        if (gm < N_) {
          const size_t oo = (size_t)(b * N_ + gm) * 256 + gn;
          const float v = xin[oo] + fmaxf(acc[i][j][r] * 0.125f + bv, 0.f);
          xout[oo] = v;
          xoutB[oo] = f2bf(v);
        }
      }
    }
  }
}

// ================= transposes =================
// xpT[(b*8+h)][d][i] = xpB[(b*200+i)*2048 + h*256 + d], zero i>=200. grid (8,8,512)
__global__ __launch_bounds__(256) void xp_transpose(const u16* __restrict__ xpB,
                                                    u16* __restrict__ xpT) {
  __shared__ u16 s[32][33];
  const int slab = blockIdx.z;
  const int b = slab >> 3, h = slab & 7;
  const int i0 = blockIdx.x * 32, d0 = blockIdx.y * 32;
  const int tx = threadIdx.x & 31, ty = threadIdx.x >> 5;
#pragma unroll
  for (int u = 0; u < 4; ++u) {
    const int i = i0 + ty + 8 * u;
    s[ty + 8 * u][tx] = (i < N_) ? xpB[(size_t)(b * N_ + i) * 2048 + h * 256 + d0 + tx] : (u16)0;
  }
  __syncthreads();
#pragma unroll
  for (int u = 0; u < 4; ++u)
    xpT[((size_t)slab * 256 + d0 + ty + 8 * u) * 256 + i0 + tx] = s[tx][ty + 8 * u];
}

// adjT[b][j][i] = adj[b][i][j]. grid (7,7,64)
__global__ __launch_bounds__(256) void adj_transpose(const int* __restrict__ adj,
                                                     int* __restrict__ adjT) {
  __shared__ int s[32][33];
  const int b = blockIdx.z;
  const int i0 = blockIdx.x * 32, j0 = blockIdx.y * 32;
  const int tx = threadIdx.x & 31, ty = threadIdx.x >> 5;
#pragma unroll
  for (int u = 0; u < 4; ++u) {
    const int i = i0 + ty + 8 * u, j = j0 + tx;
    if (i < N_ && j < N_) s[ty + 8 * u][tx] = adj[((size_t)b * N_ + i) * N_ + j];
  }
  __syncthreads();
#pragma unroll
  for (int u = 0; u < 4; ++u) {
    const int j = j0 + ty + 8 * u, i = i0 + tx;
    if (i < N_ && j < N_) adjT[((size_t)b * N_ + j) * N_ + i] = s[tx][ty + 8 * u];
  }
}

// ================= weight prep: transpose f32 [R][C] -> bf16 [C][R] =================
__device__ const int PREP_TBL[21][6] = {
    {0, 0, 0, 0, 256, 2048},
    {0, 524288, 0, 524288, 256, 2048},
    {1, 0 * 65536, 1, 0, 256, 256},      {1, 1 * 65536, 1, 65536, 256, 256},
    {1, 2 * 65536, 1, 131072, 256, 256}, {1, 4 * 65536, 1, 196608, 256, 256},
    {1, 5 * 65536, 1, 262144, 256, 256}, {1, 6 * 65536, 1, 327680, 256, 256},
    {1, 8 * 65536, 1, 393216, 256, 256}, {1, 9 * 65536, 1, 458752, 256, 256},
    {1, 10 * 65536, 1, 524288, 256, 256},
    {1, 3 * 65536, 2, 0, 256, 256},      {1, 7 * 65536, 2, 65536, 256, 256},
    {1, 11 * 65536, 2, 131072, 256, 256},
    {2, 0, 3, 0, 256, 512}, {2, 131072, 3, 131072, 256, 512}, {2, 262144, 3, 262144, 256, 512},
    {3, 0, 4, 0, 512, 256}, {3, 131072, 4, 131072, 512, 256}, {3, 262144, 4, 262144, 512, 256},
    {4, 0, 5, 0, 256, 256},
};

__global__ __launch_bounds__(256) void prep_weights(
    const float* __restrict__ gat_W, const float* __restrict__ attn_W,
    const float* __restrict__ W1, const float* __restrict__ W2,
    const float* __restrict__ Wref, u16* __restrict__ gatWT, u16* __restrict__ WqkvT,
    u16* __restrict__ WoT, u16* __restrict__ W1T, u16* __restrict__ W2T,
    u16* __restrict__ WrefT) {
  const int mi = blockIdx.y;
  const int R = PREP_TBL[mi][4], C = PREP_TBL[mi][5];
  const int tc = C / 32;
  const int tiles = (R / 32) * tc;
  if ((int)blockIdx.x >= tiles) return;
  const int sel = PREP_TBL[mi][0], dsel = PREP_TBL[mi][2];
  const float* sp = (sel == 0) ? gat_W : (sel == 1) ? attn_W : (sel == 2) ? W1 : (sel == 3) ? W2 : Wref;
  u16* dp = (dsel == 0) ? gatWT : (dsel == 1) ? WqkvT : (dsel == 2) ? WoT : (dsel == 3) ? W1T
            : (dsel == 4) ? W2T : WrefT;
  sp += PREP_TBL[mi][1];
  dp += PREP_TBL[mi][3];
  const int r0 = (blockIdx.x / tc) * 32, c0 = (blockIdx.x % tc) * 32;
  __shared__ float s[32][33];
  const int tx = threadIdx.x & 31, ty = threadIdx.x >> 5;
#pragma unroll
  for (int u = 0; u < 4; ++u) s[ty + 8 * u][tx] = sp[(size_t)(r0 + ty + 8 * u) * C + c0 + tx];
  __syncthreads();
#pragma unroll
  for (int u = 0; u < 4; ++u)
    dp[(size_t)(c0 + ty + 8 * u) * R + r0 + tx] = f2bf(s[tx][ty + 8 * u]);
}

__global__ __launch_bounds__(256) void cast_bf16(const float* __restrict__ in,
                                                 u16* __restrict__ out, int n4) {
  const int i = blockIdx.x * 256 + threadIdx.x;
  if (i >= n4) return;
  const float4 v = ((const float4*)in)[i];
  ushort4 o;
  o.x = f2bf(v.x); o.y = f2bf(v.y); o.z = f2bf(v.z); o.w = f2bf(v.w);
  ((ushort4*)out)[i] = o;
}

// ================= GAT attention =================
__global__ __launch_bounds__(256) void gat_attvec(
    const u16* __restrict__ xpB, const float* __restrict__ att_src,
    const float* __restrict__ att_dst, float* __restrict__ a_src,
    float* __restrict__ a_dst) {
  const int bn = blockIdx.x;
  const int t = threadIdx.x;
  const int h = t >> 5, s = t & 31;
  const u16* xr = xpB + (size_t)bn * 2048 + h * 256 + s * 8;
  const float* vs = att_src + h * 256 + s * 8;
  const float* vd = att_dst + h * 256 + s * 8;
  const short8 xv = *(const short8*)xr;
  float ps = 0.f, pd = 0.f;
#pragma unroll
  for (int u = 0; u < 8; ++u) {
    const float x = bf2f((u16)xv[u]);
    ps += x * vs[u];
    pd += x * vd[u];
  }
#pragma unroll
  for (int off = 16; off; off >>= 1) {
    ps += __shfl_xor(ps, off);
    pd += __shfl_xor(pd, off);
  }
  if (s == 0) {
    a_src[bn * 8 + h] = ps;
    a_dst[bn * 8 + h] = pd;
  }
}

// masked leaky-relu softmax over sources; writes bf16 [B*8][256][256] slab (k-pad zero)
__global__ __launch_bounds__(64) void gat_attn_softmax(
    const float* __restrict__ a_src, const float* __restrict__ a_dst,
    const int* __restrict__ adjT, u16* __restrict__ attnB) {
  const int id = blockIdx.x;
  const int h = id & 7;
  const int bj = id >> 3;
  const int j = bj % N_, b = bj / N_;
  const float ad = a_dst[bj * 8 + h];
  const int lane = threadIdx.x;
  const int* arow = adjT + ((size_t)b * N_ + j) * N_;
  float vals[4];
  float mx = -1e30f;
#pragma unroll
  for (int r = 0; r < 4; ++r) {
    const int i = lane + r * 64;
    float v = -1e30f;
    if (i < N_) {
      float x = ad + a_src[(b * N_ + i) * 8 + h];
      x = x > 0.f ? x : 0.2f * x;
      const bool ok = (i == j) || (arow[i] > 0);
      v = ok ? x : -1e9f;
    }
    vals[r] = v;
    mx = fmaxf(mx, v);
  }
  mx = wave_max64(mx);
  float sum = 0.f;
#pragma unroll
  for (int r = 0; r < 4; ++r) {
    const int i = lane + r * 64;
    if (i < N_) {
      const float e = __expf(vals[r] - mx);
      vals[r] = e;
      sum += e;
    }
  }
  sum = wave_sum64(sum);
  const float inv = 1.f / sum;
  u16* row = attnB + ((size_t)(b * 8 + h) * 256 + j) * 256;
#pragma unroll
  for (int r = 0; r < 4; ++r) {
    const int i = lane + r * 64;
    row[i] = (i < N_) ? f2bf(vals[r] * inv) : (u16)0;
  }
}

// ================= LayerNorm (dual f32 + bf16 out) =================
template <int PRE>
__global__ __launch_bounds__(256) void ln_kernel(
    const float* __restrict__ in1, const float* __restrict__ in2,
    const float* __restrict__ sb, float* __restrict__ out, u16* __restrict__ outB) {
  const int row = blockIdx.x, t = threadIdx.x;
  const long o = (long)row * 256 + t;
  const float v = PRE ? (in1[o] + fmaxf(in2[o], 0.f)) : in1[o];
  float s = v, q = v * v;
#pragma unroll
  for (int off = 32; off; off >>= 1) {
    s += __shfl_xor(s, off);
    q += __shfl_xor(q, off);
  }
  __shared__ float sh[8];
  const int wid = t >> 6, lane = t & 63;
  if (lane == 0) {
    sh[wid] = s;
    sh[4 + wid] = q;
  }
  __syncthreads();
  const float S = sh[0] + sh[1] + sh[2] + sh[3];
  const float Q = sh[4] + sh[5] + sh[6] + sh[7];
  const float mean = S * (1.f / 256.f);
  const float var = Q * (1.f / 256.f) - mean * mean;
  const float r = rsqrtf(var + 1e-5f);
  const float y = (v - mean) * r * sb[t] + sb[256 + t];
  out[o] = y;
  outB[o] = f2bf(y);
}

// ================= encoder attention (f32 path; qkv fused [BN][768]) =================
__global__ __launch_bounds__(64) void attn_score_softmax(
    const float* __restrict__ qkv, const int* __restrict__ adj, float* __restrict__ at) {
  const int id = blockIdx.x;  // (b*8+h)*N + qi
  const int qi = id % N_;
  const int bh = id / N_;
  const int b = bh >> 3, h = bh & 7;
  __shared__ float qs[32];
  const int lane = threadIdx.x;
  if (lane < 32) qs[lane] = qkv[(long)(b * N_ + qi) * 768 + h * 32 + lane];
  __syncthreads();
  const int* arow = adj + (long)b * N_ * N_ + (long)qi * N_;
  float vals[4];
  float mx = -1e30f;
#pragma unroll
  for (int r = 0; r < 4; ++r) {
    const int ki = lane + r * 64;
    float v = -1e30f;
    if (ki < N_) {
      if (arow[ki] > 0) {
        const float* kv = qkv + (long)(b * N_ + ki) * 768 + 256 + h * 32;
        float dot = 0.f;
#pragma unroll
        for (int d = 0; d < 32; ++d) dot += qs[d] * kv[d];
        v = dot * 0.17677669529663687f;
      } else {
        v = -1e9f;
      }
    }
    vals[r] = v;
    mx = fmaxf(mx, v);
  }
  mx = wave_max64(mx);
  float sum = 0.f;
#pragma unroll
  for (int r = 0; r < 4; ++r) {
    const int ki = lane + r * 64;
    if (ki < N_) {
      const float e = __expf(vals[r] - mx);
      vals[r] = e;
      sum += e;
    }
  }
  sum = wave_sum64(sum);
  const float inv = 1.f / sum;
  float* row = at + ((long)bh * N_ + qi) * N_;
#pragma unroll
  for (int r = 0; r < 4; ++r) {
    const int ki = lane + r * 64;
    if (ki < N_) row[ki] = vals[r] * inv;
  }
}

__global__ __launch_bounds__(256) void attn_ctx(
    const float* __restrict__ at, const float* __restrict__ qkv, u16* __restrict__ outB) {
  __shared__ float at_s[200][33];
  __shared__ float v_s[32][33];
  const int bh = blockIdx.x;
  const int b = bh >> 3, h = bh & 7;
  const float* A = at + (long)bh * N_ * N_;
  const float* V = qkv + (long)b * N_ * 768 + 512 + h * 32;
  u16* O = outB + (long)b * N_ * 256 + h * 32;
  const int tid = threadIdx.x;
  const int d = tid & 31, qg = tid >> 5;
  float acc[25];
#pragma unroll
  for (int s = 0; s < 25; ++s) acc[s] = 0.f;
  for (int k0 = 0; k0 < N_; k0 += 32) {
    const int kw = N_ - k0 < 32 ? N_ - k0 : 32;
    for (int e = tid; e < 200 * 32; e += 256) {
      const int q = e >> 5, kk = e & 31;
      at_s[q][kk] = (kk < kw) ? A[(long)q * N_ + k0 + kk] : 0.f;
    }
    for (int e = tid; e < 32 * 32; e += 256) {
      const int kk = e >> 5, dd = e & 31;
      v_s[kk][dd] = (kk < kw) ? V[(long)(k0 + kk) * 768 + dd] : 0.f;
    }
    __syncthreads();
#pragma unroll
    for (int kk = 0; kk < 32; ++kk) {
      const float vv = v_s[kk][d];
#pragma unroll
      for (int s = 0; s < 25; ++s) acc[s] += at_s[qg + 8 * s][kk] * vv;
    }
    __syncthreads();
  }
#pragma unroll
  for (int s = 0; s < 25; ++s) O[(long)(qg + 8 * s) * 256 + d] = f2bf(acc[s]);
}

// ================= LSTM + pointer =================
__global__ __launch_bounds__(256) void lstm_gates(
    const float* __restrict__ di, const float* __restrict__ dh,
    const float* __restrict__ Wih, const float* __restrict__ Whh,
    const float* __restrict__ bias, float* __restrict__ gates) {
  const int idx = blockIdx.x * 256 + threadIdx.x;
  const int b = idx >> 10, n = idx & 1023;
  const float* w1 = Wih + (long)n * 256;
  const float* w2 = Whh + (long)n * 256;
  const float* x1 = di + b * 256;
  const float* x2 = dh + b * 256;
  float s = bias[n];
  for (int k = 0; k < 256; ++k) s += x1[k] * w1[k] + x2[k] * w2[k];
  gates[idx] = s;
}

__global__ __launch_bounds__(256) void lstm_ew(
    const float* __restrict__ gates, const float* __restrict__ dc,
    float* __restrict__ h_out, float* __restrict__ c_out) {
  const int idx = blockIdx.x * 256 + threadIdx.x;
  const int b = idx >> 8, d = idx & 255;
  const float ig = sigmoidf_(gates[b * 1024 + d]);
  const float fg = sigmoidf_(gates[b * 1024 + 256 + d]);
  const float gg = tanhf(gates[b * 1024 + 512 + d]);
  const float og = sigmoidf_(gates[b * 1024 + 768 + d]);
  const float c = fg * dc[idx] + ig * gg;
  c_out[idx] = c;
  h_out[idx] = og * tanhf(c);
}

__global__ __launch_bounds__(256) void hq_gemm(
    const float* __restrict__ h, const float* __restrict__ Wq, float* __restrict__ hq) {
  const int b = blockIdx.x;
  const int n = threadIdx.x;
  float s = 0.f;
  for (int k = 0; k < 256; ++k) s += h[b * 256 + k] * Wq[k * 256 + n];
  hq[b * 256 + n] = s;
}

__global__ __launch_bounds__(64) void ptr_u(
    const float* __restrict__ pref, const float* __restrict__ hq,
    const float* __restrict__ pv, float* __restrict__ u) {
  const int row = blockIdx.x;
  const int b = row / N_;
  const int lane = threadIdx.x;
  float s = 0.f;
  for (int d = lane; d < 256; d += 64)
    s += tanhf(pref[(long)row * 256 + d] + hq[b * 256 + d]) * pv[d];
  s = wave_sum64(s);
  if (lane == 0) u[row] = s;
}

__global__ __launch_bounds__(256) void policy_softmax(
    const float* __restrict__ u, const int* __restrict__ mask, float* __restrict__ pol) {
  const int b = blockIdx.x, t = threadIdx.x;
  float val = -1e30f;
  if (t < N_) val = (mask[b * N_ + t] > 0) ? u[b * N_ + t] : -1e9f;
  float m = val;
#pragma unroll
  for (int off = 32; off; off >>= 1) m = fmaxf(m, __shfl_xor(m, off));
  __shared__ float sh[8];
  const int wid = t >> 6, lane = t & 63;
  if (lane == 0) sh[wid] = m;
  __syncthreads();
  m = fmaxf(fmaxf(sh[0], sh[1]), fmaxf(sh[2], sh[3]));
  const float e = (t < N_) ? __expf(val - m) : 0.f;
  float s = e;
#pragma unroll
  for (int off = 32; off; off >>= 1) s += __shfl_xor(s, off);
  __syncthreads();
  if (lane == 0) sh[4 + wid] = s;
  __syncthreads();
  const float S = sh[4] + sh[5] + sh[6] + sh[7];
  if (t < N_) pol[b * N_ + t] = e / S;
}

extern "C" void kernel_launch(void* const* d_in, const int* in_sizes, int n_in,
                              void* d_out, int out_size, void* d_ws, size_t ws_size,
                              hipStream_t stream) {
  const float* enc_inputs = (const float*)d_in[0];
  const float* dec_input = (const float*)d_in[1];
  const float* dec_h = (const float*)d_in[2];
  const float* dec_c = (const float*)d_in[3];
  const float* gat_W = (const float*)d_in[4];
  const float* gat_att_src = (const float*)d_in[5];
  const float* gat_att_dst = (const float*)d_in[6];
  const float* gat_bias = (const float*)d_in[7];
  const float* gat_ln = (const float*)d_in[8];
  const float* enc_attn_W = (const float*)d_in[9];
  const float* enc_attn_b = (const float*)d_in[10];
  const float* enc_ln1 = (const float*)d_in[11];
  const float* enc_ffn_W1 = (const float*)d_in[12];
  const float* enc_ffn_b1 = (const float*)d_in[13];
  const float* enc_ffn_W2 = (const float*)d_in[14];
  const float* enc_ffn_b2 = (const float*)d_in[15];
  const float* enc_ln2 = (const float*)d_in[16];
  const float* lstm_Wih = (const float*)d_in[17];
  const float* lstm_Whh = (const float*)d_in[18];
  const float* lstm_b = (const float*)d_in[19];
  const float* ptr_Wref = (const float*)d_in[20];
  const float* ptr_Wq = (const float*)d_in[21];
  const float* ptr_v = (const float*)d_in[22];
  const int* adj = (const int*)d_in[23];
  const int* mask = (const int*)d_in[24];

  float* out = (float*)d_out;
  float* policy = out;                       // 12800
  float* h_out = out + 12800;                // 16384
  float* c_out = out + 12800 + 16384;        // 16384
  float* emb = out + 12800 + 16384 + 16384;  // 3,276,800

  // ---- workspace layout ----
  char* ws = (char*)d_ws;
  char* arena = ws;                      // 186,646,528 B, phase-overlaid
  size_t o = 186646528;
  float* xbuf = (float*)(ws + o); o += 13107200;
  float* asrc = (float*)(ws + o); o += 409600;
  float* adst = (float*)(ws + o); o += 409600;
  float* gates = (float*)(ws + o); o += 262144;
  float* hq = (float*)(ws + o); o += 65536;
  float* ubuf = (float*)(ws + o); o += 51200;
  u16* xbufB = (u16*)(ws + o); o += 6553600;
  u16* embB = (u16*)(ws + o); o += 6553600;
  int* adjT = (int*)(ws + o); o += 10240000;
  u16* gatWT = (u16*)(ws + o); o += 2097152;
  u16* WqkvT = (u16*)(ws + o); o += 1179648;
  u16* WoT = (u16*)(ws + o); o += 393216;
  u16* W1T = (u16*)(ws + o); o += 786432;
  u16* W2T = (u16*)(ws + o); o += 786432;
  u16* WrefT = (u16*)(ws + o); o += 131072;
  if (ws_size < o) fprintf(stderr, "kernel_launch: ws too small (%zu < %zu)\n", ws_size, o);
  // GAT-phase arena views
  u16* xpB = (u16*)arena;                      // [BN][2048] bf16
  u16* xpT = (u16*)(arena + 52428800);         // [512][256][256] bf16
  u16* attnB = (u16*)(arena + 119537664);      // [512][256][256] bf16
  u16* encB = (u16*)(arena + 119537664);       // [BN][256] bf16 (dead before softmax)
  // encoder-phase arena views
  float* qkv = (float*)arena;                  // [BN][768] f32
  float* attnF = (float*)(arena + 39321600);   // [B*8][200][200] f32
  u16* ffnB = (u16*)(arena + 121241600);       // [BN][512] bf16
  u16* ctxB = (u16*)(arena + 134348800);       // [BN][256] bf16
  float* tmp = (float*)(arena + 140902400);    // [BN][256] f32
  float* pref = (float*)arena;                 // pointer phase

  // ---- prep ----
  prep_weights<<<dim3(512, 21), 256, 0, stream>>>(gat_W, enc_attn_W, enc_ffn_W1, enc_ffn_W2,
                                                  ptr_Wref, gatWT, WqkvT, WoT, W1T, W2T, WrefT);
  cast_bf16<<<3200, 256, 0, stream>>>(enc_inputs, encB, 819200);
  adj_transpose<<<dim3(7, 7, 64), 256, 0, stream>>>(adj, adjT);

  // ---- GAT stack ----
  for (int g = 0; g < G_; ++g) {
    const u16* AinB = (g == 0) ? encB : xbufB;
    const float* xin = (g == 0) ? enc_inputs : xbuf;
    gemm_bf16<0, false, false, true><<<dim3(100, 16), 256, 0, stream>>>(
        AinB, gatWT + (size_t)g * 524288, nullptr, nullptr, nullptr, xpB, BN_, 2048, 256);
    gat_attvec<<<BN_, 256, 0, stream>>>(xpB, gat_att_src + g * 2048, gat_att_dst + g * 2048,
                                        asrc, adst);
    gat_attn_softmax<<<BN_ * NH_, 64, 0, stream>>>(asrc, adst, adjT, attnB);
    xp_transpose<<<dim3(8, 8, 512), 256, 0, stream>>>(xpB, xpT);
    gat_msg_mfma<<<dim3(2, 2, 64), 256, 0, stream>>>(attnB, xpT, gat_bias + g * H_, xin,
                                                     xbuf, xbufB);
  }
  ln_kernel<1><<<BN_, 256, 0, stream>>>(enc_inputs, xbuf, gat_ln, emb, embB);

  // ---- Transformer encoder ----
  for (int l = 0; l < L_; ++l) {
    gemm_bf16<0, true, false, false><<<dim3(100, 6), 256, 0, stream>>>(
        embB, WqkvT + (size_t)l * 196608, enc_attn_b + l * 1024, nullptr, qkv, nullptr,
        BN_, 768, 256);
    attn_score_softmax<<<B_ * NH_ * N_, 64, 0, stream>>>(qkv, adj, attnF);
    attn_ctx<<<B_ * NH_, 256, 0, stream>>>(attnF, qkv, ctxB);
    gemm_bf16<0, true, true, false><<<dim3(100, 2), 256, 0, stream>>>(
        ctxB, WoT + (size_t)l * 65536, enc_attn_b + l * 1024 + 768, emb, tmp, nullptr,
        BN_, 256, 256);
    ln_kernel<0><<<BN_, 256, 0, stream>>>(tmp, nullptr, enc_ln1 + l * 512, emb, embB);
    gemm_bf16<1, true, false, true><<<dim3(100, 4), 256, 0, stream>>>(
        embB, W1T + (size_t)l * 131072, enc_ffn_b1 + l * 512, nullptr, nullptr, ffnB,
        BN_, 512, 256);
    gemm_bf16<0, true, true, false><<<dim3(100, 2), 256, 0, stream>>>(
        ffnB, W2T + (size_t)l * 131072, enc_ffn_b2 + l * 256, emb, tmp, nullptr,
        BN_, 256, 512);
    ln_kernel<0><<<BN_, 256, 0, stream>>>(tmp, nullptr, enc_ln2 + l * 512, emb, embB);
  }

  // ---- LSTM + pointer ----
  lstm_gates<<<256, 256, 0, stream>>>(dec_input, dec_h, lstm_Wih, lstm_Whh, lstm_b, gates);
  lstm_ew<<<64, 256, 0, stream>>>(gates, dec_c, h_out, c_out);
  hq_gemm<<<64, 256, 0, stream>>>(h_out, ptr_Wq, hq);
  gemm_bf16<0, false, false, false><<<dim3(100, 2), 256, 0, stream>>>(
      embB, WrefT, nullptr, nullptr, pref, nullptr, BN_, 256, 256);
  ptr_u<<<BN_, 64, 0, stream>>>(pref, hq, ptr_v, ubuf);
  policy_softmax<<<B_, 256, 0, stream>>>(ubuf, mask, policy);
}

// Round 5
// 854.826 us; speedup vs baseline: 5.2033x; 2.2412x over previous
//
#include <hip/hip_runtime.h>
#include <cstdio>
#include <math.h>

static constexpr int B_ = 64, N_ = 200, H_ = 256, NH_ = 8, G_ = 2, L_ = 3, F_ = 512;
static constexpr int BN_ = B_ * N_;  // 12800

typedef unsigned short u16;
typedef __attribute__((ext_vector_type(8))) short short8;
typedef __attribute__((ext_vector_type(4))) float f32x4;

#define LDSP(p) ((__attribute__((address_space(3))) unsigned int*)(p))
#define GLBP(p) ((const __attribute__((address_space(1))) unsigned int*)(p))

__device__ __forceinline__ float wave_sum64(float v) {
#pragma unroll
  for (int off = 32; off; off >>= 1) v += __shfl_xor(v, off);
  return v;
}
__device__ __forceinline__ float wave_max64(float v) {
#pragma unroll
  for (int off = 32; off; off >>= 1) v = fmaxf(v, __shfl_xor(v, off));
  return v;
}
__device__ __forceinline__ float sigmoidf_(float x) { return 1.f / (1.f + __expf(-x)); }
__device__ __forceinline__ u16 f2bf(float x) {  // RNE f32->bf16
  unsigned u = __float_as_uint(x);
  return (u16)((u + 0x7FFFu + ((u >> 16) & 1u)) >> 16);
}
__device__ __forceinline__ float bf2f(u16 x) { return __uint_as_float((unsigned)x << 16); }

// ================= bf16 MFMA GEMM =================
// C[M][Nn] = act(A @ Bt^T + bias + res). A: bf16 [M][K]; Bt: bf16 [Nn][K].
// Tile 128x128, BK=64, 4 waves (2x2 of 64x64). K%64==0, M%128==0, Nn%128==0.
template <int ACT, bool HAS_BIAS, bool HAS_RES, bool OUT_BF>
__global__ __launch_bounds__(256) void gemm_bf16(
    const u16* __restrict__ A, const u16* __restrict__ Bt,
    const float* __restrict__ bias, const float* __restrict__ res,
    float* __restrict__ Cf, u16* __restrict__ Cb, int M, int Nn, int K) {
  __shared__ u16 As[128 * 64];
  __shared__ u16 Bs[128 * 64];
  char* asB = (char*)As;
  char* bsB = (char*)Bs;
  const int tid = threadIdx.x;
  const int m0 = blockIdx.x * 128, n0 = blockIdx.y * 128;
  const int lane = tid & 63;
  const int wid = tid >> 6;
  const int wr = (wid >> 1) * 64, wc = (wid & 1) * 64;
  const int Kb = K * 2;
  const char* Ab = (const char*)A + (size_t)m0 * Kb;
  const char* Bb = (const char*)Bt + (size_t)n0 * Kb;
  f32x4 acc[4][4];
#pragma unroll
  for (int i = 0; i < 4; ++i)
#pragma unroll
    for (int j = 0; j < 4; ++j)
#pragma unroll
      for (int r = 0; r < 4; ++r) acc[i][j][r] = 0.f;

  for (int k0 = 0; k0 < K; k0 += 64) {
    if (k0) __syncthreads();
#pragma unroll
    for (int it = 0; it < 4; ++it) {
      const unsigned o = (unsigned)(it * 256 + tid) * 16;  // linear LDS byte offset
      const int row = o >> 7;
      const unsigned bc = (o & 127u) ^ (unsigned)((row & 7) << 4);  // inverse-swizzled src col
      const unsigned wb = o & ~1023u;  // wave-uniform LDS base
      __builtin_amdgcn_global_load_lds(GLBP(Ab + (size_t)row * Kb + k0 * 2 + bc),
                                       LDSP(asB + wb), 16, 0, 0);
      __builtin_amdgcn_global_load_lds(GLBP(Bb + (size_t)row * Kb + k0 * 2 + bc),
                                       LDSP(bsB + wb), 16, 0, 0);
    }
    __syncthreads();
#pragma unroll
    for (int kk = 0; kk < 2; ++kk) {
      short8 aF[4], bF[4];
#pragma unroll
      for (int i = 0; i < 4; ++i) {
        const int ar = wr + i * 16 + (lane & 15);
        const unsigned ac = (unsigned)(kk * 64 + (lane >> 4) * 16) ^ (unsigned)((ar & 7) << 4);
        aF[i] = *(const short8*)(asB + ar * 128 + ac);
        const int br = wc + i * 16 + (lane & 15);
        const unsigned bc2 = (unsigned)(kk * 64 + (lane >> 4) * 16) ^ (unsigned)((br & 7) << 4);
        bF[i] = *(const short8*)(bsB + br * 128 + bc2);
      }
#pragma unroll
      for (int i = 0; i < 4; ++i)
#pragma unroll
        for (int j = 0; j < 4; ++j)
          acc[i][j] = __builtin_amdgcn_mfma_f32_16x16x32_bf16(aF[i], bF[j], acc[i][j], 0, 0, 0);
    }
  }
  // epilogue: C/D layout col=lane&15, row=(lane>>4)*4+reg  [m89]
#pragma unroll
  for (int i = 0; i < 4; ++i) {
    const int gm0 = m0 + wr + i * 16 + (lane >> 4) * 4;
#pragma unroll
    for (int j = 0; j < 4; ++j) {
      const int gn = n0 + wc + j * 16 + (lane & 15);
      const float bv = HAS_BIAS ? bias[gn] : 0.f;
#pragma unroll
      for (int r = 0; r < 4; ++r) {
        const int gm = gm0 + r;
        float v = acc[i][j][r] + bv;
        if (HAS_RES) v += res[(size_t)gm * Nn + gn];
        if (ACT == 1) v = fmaxf(v, 0.f);
        if (OUT_BF)
          Cb[(size_t)gm * Nn + gn] = f2bf(v);
        else
          Cf[(size_t)gm * Nn + gn] = v;
      }
    }
  }
}

// ================= GAT message MFMA =================
__global__ __launch_bounds__(256) void gat_msg_mfma(
    const u16* __restrict__ attnB, const u16* __restrict__ xpT,
    const float* __restrict__ bias, const float* __restrict__ xin,
    float* __restrict__ xout, u16* __restrict__ xoutB) {
  __shared__ u16 As[128 * 64];
  __shared__ u16 Bs[128 * 64];
  char* asB = (char*)As;
  char* bsB = (char*)Bs;
  const int tid = threadIdx.x;
  const int m0 = blockIdx.x * 128, n0 = blockIdx.y * 128;
  const int b = blockIdx.z;
  const int lane = tid & 63, wid = tid >> 6;
  const int wr = (wid >> 1) * 64, wc = (wid & 1) * 64;
  f32x4 acc[4][4];
#pragma unroll
  for (int i = 0; i < 4; ++i)
#pragma unroll
    for (int j = 0; j < 4; ++j)
#pragma unroll
      for (int r = 0; r < 4; ++r) acc[i][j][r] = 0.f;
  const char* baseA = (const char*)attnB + ((size_t)b << 20) + (size_t)m0 * 512;
  const char* baseB = (const char*)xpT + ((size_t)b << 20) + (size_t)n0 * 512;
  for (int t = 0; t < 32; ++t) {
    const size_t hoff = (size_t)(t >> 2) * 131072;
    const int k0 = (t & 3) * 64;
    if (t) __syncthreads();
#pragma unroll
    for (int it = 0; it < 4; ++it) {
      const unsigned o = (unsigned)(it * 256 + tid) * 16;
      const int row = o >> 7;
      const unsigned bc = (o & 127u) ^ (unsigned)((row & 7) << 4);
      const unsigned wb = o & ~1023u;
      __builtin_amdgcn_global_load_lds(GLBP(baseA + hoff + (size_t)row * 512 + k0 * 2 + bc),
                                       LDSP(asB + wb), 16, 0, 0);
      __builtin_amdgcn_global_load_lds(GLBP(baseB + hoff + (size_t)row * 512 + k0 * 2 + bc),
                                       LDSP(bsB + wb), 16, 0, 0);
    }
    __syncthreads();
#pragma unroll
    for (int kk = 0; kk < 2; ++kk) {
      short8 aF[4], bF[4];
#pragma unroll
      for (int i = 0; i < 4; ++i) {
        const int ar = wr + i * 16 + (lane & 15);
        const unsigned ac = (unsigned)(kk * 64 + (lane >> 4) * 16) ^ (unsigned)((ar & 7) << 4);
        aF[i] = *(const short8*)(asB + ar * 128 + ac);
        const int br = wc + i * 16 + (lane & 15);
        const unsigned bc2 = (unsigned)(kk * 64 + (lane >> 4) * 16) ^ (unsigned)((br & 7) << 4);
        bF[i] = *(const short8*)(bsB + br * 128 + bc2);
      }
#pragma unroll
      for (int i = 0; i < 4; ++i)
#pragma unroll
        for (int j = 0; j < 4; ++j)
          acc[i][j] = __builtin_amdgcn_mfma_f32_16x16x32_bf16(aF[i], bF[j], acc[i][j], 0, 0, 0);
    }
  }
#pragma unroll
  for (int i = 0; i < 4; ++i) {
    const int gm0 = m0 + wr + i * 16 + (lane >> 4) * 4;
#pragma unroll
    for (int j = 0; j < 4; ++j) {
      const int gn = n0 + wc + j * 16 + (lane & 15);
      const float bv = bias[gn];
#pragma unroll
      for (int r = 0; r < 4; ++r) {
        const int gm = gm0 + r;
        if (gm < N_) {
          const size_t oo = (size_t)(b * N_ + gm) * 256 + gn;
          const float v = xin[oo] + fmaxf(acc[i][j][r] * 0.125f + bv, 0.f);
          xout[oo] = v;
          xoutB[oo] = f2bf(v);
        }
      }
    }
  }
}

// ================= fused encoder attention =================
// grid 512 = b*8+h, 256 thr (4 waves). ctx[b,q,h*32+d] = softmax(mask(QK^T/sqrt32)) @ V
__global__ __launch_bounds__(256) void attn_fused(
    const u16* __restrict__ qkvB, const unsigned* __restrict__ adjW,
    u16* __restrict__ ctxB) {
  __shared__ __align__(16) u16 K_lds[208 * 40];    // [kv][40] stride 80B
  __shared__ __align__(16) u16 V_lds[32 * 232];    // [d][232] stride 464B (V^T)
  __shared__ __align__(16) u16 P_lds[4][16 * 232]; // per-wave [16 q][232 kv]
  const int bh = blockIdx.x;
  const int b = bh >> 3, h = bh & 7;
  const int tid = threadIdx.x, lane = tid & 63, wid = tid >> 6;
  const u16* qb = qkvB + (size_t)b * 200 * 768;
  // stage K rows + V transposed
  for (int e = tid; e < 200 * 32; e += 256) {
    const int kv = e >> 5, d = e & 31;
    K_lds[kv * 40 + d] = qb[(size_t)kv * 768 + 256 + h * 32 + d];
    V_lds[d * 232 + kv] = qb[(size_t)kv * 768 + 512 + h * 32 + d];
  }
  // zero V pad rows kv 200..223 (avoid NaN poison: P_pad(0) * V_garbage)
  for (int e = tid; e < 32 * 24; e += 256) V_lds[(e / 24) * 232 + 200 + (e % 24)] = 0;
  const int g = lane >> 4, c = lane & 15;
  u16* Pw = P_lds[wid];
  // zero P pad cols 208..223 for this wave
  for (int e = lane; e < 16 * 16; e += 64) Pw[(e >> 4) * 232 + 208 + (e & 15)] = 0;
  __syncthreads();
  // cache K fragments (13 n-tiles)
  short8 kf[13];
#pragma unroll
  for (int nt = 0; nt < 13; ++nt)
    kf[nt] = *(const short8*)&K_lds[(nt * 16 + c) * 40 + g * 8];
  const float scale = 0.17677669529663687f;  // 1/sqrt(32)
  for (int t = 0; t < 4; ++t) {
    const int m0 = (wid * 4 + t) * 16;
    // Q fragment from global (row-clamped; garbage rows stay in garbage outputs)
    int qrow = b * 200 + m0 + c;
    if (qrow > BN_ - 1) qrow = BN_ - 1;
    const short8 qf = *(const short8*)&qkvB[(size_t)qrow * 768 + h * 32 + g * 8];
    // S = Q@K^T
    f32x4 acc[13];
#pragma unroll
    for (int nt = 0; nt < 13; ++nt) {
      f32x4 z = {0.f, 0.f, 0.f, 0.f};
      acc[nt] = __builtin_amdgcn_mfma_f32_16x16x32_bf16(qf, kf[nt], z, 0, 0, 0);
    }
    // adj bitmask for this lane-group's 4 rows
    unsigned m8[4][8];
#pragma unroll
    for (int r = 0; r < 4; ++r) {
      const uint4* mp = (const uint4*)(adjW + ((size_t)b * 256 + m0 + g * 4 + r) * 8);
      const uint4 a0 = mp[0], a1 = mp[1];
      m8[r][0] = a0.x; m8[r][1] = a0.y; m8[r][2] = a0.z; m8[r][3] = a0.w;
      m8[r][4] = a1.x; m8[r][5] = a1.y; m8[r][6] = a1.z; m8[r][7] = a1.w;
    }
    // mask + scale
    float mx[4] = {-3e38f, -3e38f, -3e38f, -3e38f};
#pragma unroll
    for (int nt = 0; nt < 13; ++nt) {
      const int col = nt * 16 + c;
      const float sentinel = (col < 200) ? -1e9f : -2e9f;
#pragma unroll
      for (int r = 0; r < 4; ++r) {
        const bool ok = (m8[r][nt >> 1] >> (((nt & 1) << 4) + c)) & 1u;
        const float v = ok ? acc[nt][r] * scale : sentinel;
        acc[nt][r] = v;
        mx[r] = fmaxf(mx[r], v);
      }
    }
    // row reduce max over 16-lane group
#pragma unroll
    for (int off = 1; off < 16; off <<= 1)
#pragma unroll
      for (int r = 0; r < 4; ++r) mx[r] = fmaxf(mx[r], __shfl_xor(mx[r], off));
    // exp + sum
    float sm[4] = {0.f, 0.f, 0.f, 0.f};
#pragma unroll
    for (int nt = 0; nt < 13; ++nt)
#pragma unroll
      for (int r = 0; r < 4; ++r) {
        const float e = __expf(acc[nt][r] - mx[r]);
        acc[nt][r] = e;
        sm[r] += e;
      }
#pragma unroll
    for (int off = 1; off < 16; off <<= 1)
#pragma unroll
      for (int r = 0; r < 4; ++r) sm[r] += __shfl_xor(sm[r], off);
#pragma unroll
    for (int r = 0; r < 4; ++r) sm[r] = 1.f / sm[r];
    // P -> per-wave LDS (bf16)
#pragma unroll
    for (int nt = 0; nt < 13; ++nt)
#pragma unroll
      for (int r = 0; r < 4; ++r)
        Pw[(g * 4 + r) * 232 + nt * 16 + c] = f2bf(acc[nt][r] * sm[r]);
    // ctx = P @ V  (K=224, 7 k-tiles; d-tiles 2)
    f32x4 o0 = {0.f, 0.f, 0.f, 0.f}, o1 = {0.f, 0.f, 0.f, 0.f};
#pragma unroll
    for (int kt = 0; kt < 7; ++kt) {
      const short8 pf = *(const short8*)&Pw[c * 232 + kt * 32 + g * 8];
      const short8 v0 = *(const short8*)&V_lds[c * 232 + kt * 32 + g * 8];
      const short8 v1 = *(const short8*)&V_lds[(16 + c) * 232 + kt * 32 + g * 8];
      o0 = __builtin_amdgcn_mfma_f32_16x16x32_bf16(pf, v0, o0, 0, 0, 0);
      o1 = __builtin_amdgcn_mfma_f32_16x16x32_bf16(pf, v1, o1, 0, 0, 0);
    }
#pragma unroll
    for (int r = 0; r < 4; ++r) {
      const int q = m0 + g * 4 + r;
      if (q < N_) {
        u16* od = ctxB + ((size_t)(b * N_ + q)) * 256 + h * 32;
        od[c] = f2bf(o0[r]);
        od[16 + c] = f2bf(o1[r]);
      }
    }
  }
}

// adjW[b][row][w] = bitmask of adj[b][row][w*32..] > 0 (rows>=200, w==7 -> 0)
__global__ __launch_bounds__(256) void adj_bits(const int* __restrict__ adj,
                                                unsigned* __restrict__ adjW) {
  const int b = blockIdx.x;
  for (int e = threadIdx.x; e < 256 * 8; e += 256) {
    const int row = e >> 3, w = e & 7;
    unsigned bits = 0u;
    if (row < N_ && w < 7) {
      const int base = w * 32;
      const int lim = (N_ - base) < 32 ? (N_ - base) : 32;
      const int* ar = adj + ((size_t)b * N_ + row) * N_ + base;
      for (int i = 0; i < lim; ++i) bits |= (ar[i] > 0 ? 1u : 0u) << i;
    }
    adjW[((size_t)b * 256 + row) * 8 + w] = bits;
  }
}

// ================= transposes =================
__global__ __launch_bounds__(256) void xp_transpose(const u16* __restrict__ xpB,
                                                    u16* __restrict__ xpT) {
  __shared__ u16 s[32][33];
  const int slab = blockIdx.z;
  const int b = slab >> 3, h = slab & 7;
  const int i0 = blockIdx.x * 32, d0 = blockIdx.y * 32;
  const int tx = threadIdx.x & 31, ty = threadIdx.x >> 5;
#pragma unroll
  for (int u = 0; u < 4; ++u) {
    const int i = i0 + ty + 8 * u;
    s[ty + 8 * u][tx] = (i < N_) ? xpB[(size_t)(b * N_ + i) * 2048 + h * 256 + d0 + tx] : (u16)0;
  }
  __syncthreads();
#pragma unroll
  for (int u = 0; u < 4; ++u)
    xpT[((size_t)slab * 256 + d0 + ty + 8 * u) * 256 + i0 + tx] = s[tx][ty + 8 * u];
}

__global__ __launch_bounds__(256) void adj_transpose(const int* __restrict__ adj,
                                                     int* __restrict__ adjT) {
  __shared__ int s[32][33];
  const int b = blockIdx.z;
  const int i0 = blockIdx.x * 32, j0 = blockIdx.y * 32;
  const int tx = threadIdx.x & 31, ty = threadIdx.x >> 5;
#pragma unroll
  for (int u = 0; u < 4; ++u) {
    const int i = i0 + ty + 8 * u, j = j0 + tx;
    if (i < N_ && j < N_) s[ty + 8 * u][tx] = adj[((size_t)b * N_ + i) * N_ + j];
  }
  __syncthreads();
#pragma unroll
  for (int u = 0; u < 4; ++u) {
    const int j = j0 + ty + 8 * u, i = i0 + tx;
    if (i < N_ && j < N_) adjT[((size_t)b * N_ + j) * N_ + i] = s[tx][ty + 8 * u];
  }
}

// ================= weight prep =================
__device__ const int PREP_TBL[21][6] = {
    {0, 0, 0, 0, 256, 2048},
    {0, 524288, 0, 524288, 256, 2048},
    {1, 0 * 65536, 1, 0, 256, 256},      {1, 1 * 65536, 1, 65536, 256, 256},
    {1, 2 * 65536, 1, 131072, 256, 256}, {1, 4 * 65536, 1, 196608, 256, 256},
    {1, 5 * 65536, 1, 262144, 256, 256}, {1, 6 * 65536, 1, 327680, 256, 256},
    {1, 8 * 65536, 1, 393216, 256, 256}, {1, 9 * 65536, 1, 458752, 256, 256},
    {1, 10 * 65536, 1, 524288, 256, 256},
    {1, 3 * 65536, 2, 0, 256, 256},      {1, 7 * 65536, 2, 65536, 256, 256},
    {1, 11 * 65536, 2, 131072, 256, 256},
    {2, 0, 3, 0, 256, 512}, {2, 131072, 3, 131072, 256, 512}, {2, 262144, 3, 262144, 256, 512},
    {3, 0, 4, 0, 512, 256}, {3, 131072, 4, 131072, 512, 256}, {3, 262144, 4, 262144, 512, 256},
    {4, 0, 5, 0, 256, 256},
};

__global__ __launch_bounds__(256) void prep_weights(
    const float* __restrict__ gat_W, const float* __restrict__ attn_W,
    const float* __restrict__ W1, const float* __restrict__ W2,
    const float* __restrict__ Wref, u16* __restrict__ gatWT, u16* __restrict__ WqkvT,
    u16* __restrict__ WoT, u16* __restrict__ W1T, u16* __restrict__ W2T,
    u16* __restrict__ WrefT) {
  const int mi = blockIdx.y;
  const int R = PREP_TBL[mi][4], C = PREP_TBL[mi][5];
  const int tc = C / 32;
  const int tiles = (R / 32) * tc;
  if ((int)blockIdx.x >= tiles) return;
  const int sel = PREP_TBL[mi][0], dsel = PREP_TBL[mi][2];
  const float* sp = (sel == 0) ? gat_W : (sel == 1) ? attn_W : (sel == 2) ? W1 : (sel == 3) ? W2 : Wref;
  u16* dp = (dsel == 0) ? gatWT : (dsel == 1) ? WqkvT : (dsel == 2) ? WoT : (dsel == 3) ? W1T
            : (dsel == 4) ? W2T : WrefT;
  sp += PREP_TBL[mi][1];
  dp += PREP_TBL[mi][3];
  const int r0 = (blockIdx.x / tc) * 32, c0 = (blockIdx.x % tc) * 32;
  __shared__ float s[32][33];
  const int tx = threadIdx.x & 31, ty = threadIdx.x >> 5;
#pragma unroll
  for (int u = 0; u < 4; ++u) s[ty + 8 * u][tx] = sp[(size_t)(r0 + ty + 8 * u) * C + c0 + tx];
  __syncthreads();
#pragma unroll
  for (int u = 0; u < 4; ++u)
    dp[(size_t)(c0 + ty + 8 * u) * R + r0 + tx] = f2bf(s[tx][ty + 8 * u]);
}

__global__ __launch_bounds__(256) void cast_bf16(const float* __restrict__ in,
                                                 u16* __restrict__ out, int n4) {
  const int i = blockIdx.x * 256 + threadIdx.x;
  if (i >= n4) return;
  const float4 v = ((const float4*)in)[i];
  ushort4 o;
  o.x = f2bf(v.x); o.y = f2bf(v.y); o.z = f2bf(v.z); o.w = f2bf(v.w);
  ((ushort4*)out)[i] = o;
}

// ================= GAT attention =================
__global__ __launch_bounds__(256) void gat_attvec(
    const u16* __restrict__ xpB, const float* __restrict__ att_src,
    const float* __restrict__ att_dst, float* __restrict__ a_src,
    float* __restrict__ a_dst) {
  const int bn = blockIdx.x;
  const int t = threadIdx.x;
  const int h = t >> 5, s = t & 31;
  const u16* xr = xpB + (size_t)bn * 2048 + h * 256 + s * 8;
  const float* vs = att_src + h * 256 + s * 8;
  const float* vd = att_dst + h * 256 + s * 8;
  const short8 xv = *(const short8*)xr;
  float ps = 0.f, pd = 0.f;
#pragma unroll
  for (int u = 0; u < 8; ++u) {
    const float x = bf2f((u16)xv[u]);
    ps += x * vs[u];
    pd += x * vd[u];
  }
#pragma unroll
  for (int off = 16; off; off >>= 1) {
    ps += __shfl_xor(ps, off);
    pd += __shfl_xor(pd, off);
  }
  if (s == 0) {
    a_src[bn * 8 + h] = ps;
    a_dst[bn * 8 + h] = pd;
  }
}

__global__ __launch_bounds__(64) void gat_attn_softmax(
    const float* __restrict__ a_src, const float* __restrict__ a_dst,
    const int* __restrict__ adjT, u16* __restrict__ attnB) {
  const int id = blockIdx.x;
  const int h = id & 7;
  const int bj = id >> 3;
  const int j = bj % N_, b = bj / N_;
  const float ad = a_dst[bj * 8 + h];
  const int lane = threadIdx.x;
  const int* arow = adjT + ((size_t)b * N_ + j) * N_;
  float vals[4];
  float mx = -1e30f;
#pragma unroll
  for (int r = 0; r < 4; ++r) {
    const int i = lane + r * 64;
    float v = -1e30f;
    if (i < N_) {
      float x = ad + a_src[(b * N_ + i) * 8 + h];
      x = x > 0.f ? x : 0.2f * x;
      const bool ok = (i == j) || (arow[i] > 0);
      v = ok ? x : -1e9f;
    }
    vals[r] = v;
    mx = fmaxf(mx, v);
  }
  mx = wave_max64(mx);
  float sum = 0.f;
#pragma unroll
  for (int r = 0; r < 4; ++r) {
    const int i = lane + r * 64;
    if (i < N_) {
      const float e = __expf(vals[r] - mx);
      vals[r] = e;
      sum += e;
    }
  }
  sum = wave_sum64(sum);
  const float inv = 1.f / sum;
  u16* row = attnB + ((size_t)(b * 8 + h) * 256 + j) * 256;
#pragma unroll
  for (int r = 0; r < 4; ++r) {
    const int i = lane + r * 64;
    row[i] = (i < N_) ? f2bf(vals[r] * inv) : (u16)0;
  }
}

// ================= LayerNorm (dual f32 + bf16 out) =================
template <int PRE>
__global__ __launch_bounds__(256) void ln_kernel(
    const float* __restrict__ in1, const float* __restrict__ in2,
    const float* __restrict__ sb, float* __restrict__ out, u16* __restrict__ outB) {
  const int row = blockIdx.x, t = threadIdx.x;
  const long o = (long)row * 256 + t;
  const float v = PRE ? (in1[o] + fmaxf(in2[o], 0.f)) : in1[o];
  float s = v, q = v * v;
#pragma unroll
  for (int off = 32; off; off >>= 1) {
    s += __shfl_xor(s, off);
    q += __shfl_xor(q, off);
  }
  __shared__ float sh[8];
  const int wid = t >> 6, lane = t & 63;
  if (lane == 0) {
    sh[wid] = s;
    sh[4 + wid] = q;
  }
  __syncthreads();
  const float S = sh[0] + sh[1] + sh[2] + sh[3];
  const float Q = sh[4] + sh[5] + sh[6] + sh[7];
  const float mean = S * (1.f / 256.f);
  const float var = Q * (1.f / 256.f) - mean * mean;
  const float r = rsqrtf(var + 1e-5f);
  const float y = (v - mean) * r * sb[t] + sb[256 + t];
  out[o] = y;
  outB[o] = f2bf(y);
}

// ================= LSTM + pointer =================
__global__ __launch_bounds__(256) void lstm_gates(
    const float* __restrict__ di, const float* __restrict__ dh,
    const float* __restrict__ Wih, const float* __restrict__ Whh,
    const float* __restrict__ bias, float* __restrict__ gates) {
  const int idx = blockIdx.x * 256 + threadIdx.x;
  const int b = idx >> 10, n = idx & 1023;
  const float* w1 = Wih + (long)n * 256;
  const float* w2 = Whh + (long)n * 256;
  const float* x1 = di + b * 256;
  const float* x2 = dh + b * 256;
  float s = bias[n];
  for (int k = 0; k < 256; ++k) s += x1[k] * w1[k] + x2[k] * w2[k];
  gates[idx] = s;
}

__global__ __launch_bounds__(256) void lstm_ew(
    const float* __restrict__ gates, const float* __restrict__ dc,
    float* __restrict__ h_out, float* __restrict__ c_out) {
  const int idx = blockIdx.x * 256 + threadIdx.x;
  const int b = idx >> 8, d = idx & 255;
  const float ig = sigmoidf_(gates[b * 1024 + d]);
  const float fg = sigmoidf_(gates[b * 1024 + 256 + d]);
  const float gg = tanhf(gates[b * 1024 + 512 + d]);
  const float og = sigmoidf_(gates[b * 1024 + 768 + d]);
  const float c = fg * dc[idx] + ig * gg;
  c_out[idx] = c;
  h_out[idx] = og * tanhf(c);
}

__global__ __launch_bounds__(256) void hq_gemm(
    const float* __restrict__ h, const float* __restrict__ Wq, float* __restrict__ hq) {
  const int b = blockIdx.x;
  const int n = threadIdx.x;
  float s = 0.f;
  for (int k = 0; k < 256; ++k) s += h[b * 256 + k] * Wq[k * 256 + n];
  hq[b * 256 + n] = s;
}

__global__ __launch_bounds__(64) void ptr_u(
    const float* __restrict__ pref, const float* __restrict__ hq,
    const float* __restrict__ pv, float* __restrict__ u) {
  const int row = blockIdx.x;
  const int b = row / N_;
  const int lane = threadIdx.x;
  float s = 0.f;
  for (int d = lane; d < 256; d += 64)
    s += tanhf(pref[(long)row * 256 + d] + hq[b * 256 + d]) * pv[d];
  s = wave_sum64(s);
  if (lane == 0) u[row] = s;
}

__global__ __launch_bounds__(256) void policy_softmax(
    const float* __restrict__ u, const int* __restrict__ mask, float* __restrict__ pol) {
  const int b = blockIdx.x, t = threadIdx.x;
  float val = -1e30f;
  if (t < N_) val = (mask[b * N_ + t] > 0) ? u[b * N_ + t] : -1e9f;
  float m = val;
#pragma unroll
  for (int off = 32; off; off >>= 1) m = fmaxf(m, __shfl_xor(m, off));
  __shared__ float sh[8];
  const int wid = t >> 6, lane = t & 63;
  if (lane == 0) sh[wid] = m;
  __syncthreads();
  m = fmaxf(fmaxf(sh[0], sh[1]), fmaxf(sh[2], sh[3]));
  const float e = (t < N_) ? __expf(val - m) : 0.f;
  float s = e;
#pragma unroll
  for (int off = 32; off; off >>= 1) s += __shfl_xor(s, off);
  __syncthreads();
  if (lane == 0) sh[4 + wid] = s;
  __syncthreads();
  const float S = sh[4] + sh[5] + sh[6] + sh[7];
  if (t < N_) pol[b * N_ + t] = e / S;
}

extern "C" void kernel_launch(void* const* d_in, const int* in_sizes, int n_in,
                              void* d_out, int out_size, void* d_ws, size_t ws_size,
                              hipStream_t stream) {
  const float* enc_inputs = (const float*)d_in[0];
  const float* dec_input = (const float*)d_in[1];
  const float* dec_h = (const float*)d_in[2];
  const float* dec_c = (const float*)d_in[3];
  const float* gat_W = (const float*)d_in[4];
  const float* gat_att_src = (const float*)d_in[5];
  const float* gat_att_dst = (const float*)d_in[6];
  const float* gat_bias = (const float*)d_in[7];
  const float* gat_ln = (const float*)d_in[8];
  const float* enc_attn_W = (const float*)d_in[9];
  const float* enc_attn_b = (const float*)d_in[10];
  const float* enc_ln1 = (const float*)d_in[11];
  const float* enc_ffn_W1 = (const float*)d_in[12];
  const float* enc_ffn_b1 = (const float*)d_in[13];
  const float* enc_ffn_W2 = (const float*)d_in[14];
  const float* enc_ffn_b2 = (const float*)d_in[15];
  const float* enc_ln2 = (const float*)d_in[16];
  const float* lstm_Wih = (const float*)d_in[17];
  const float* lstm_Whh = (const float*)d_in[18];
  const float* lstm_b = (const float*)d_in[19];
  const float* ptr_Wref = (const float*)d_in[20];
  const float* ptr_Wq = (const float*)d_in[21];
  const float* ptr_v = (const float*)d_in[22];
  const int* adj = (const int*)d_in[23];
  const int* mask = (const int*)d_in[24];

  float* out = (float*)d_out;
  float* policy = out;                       // 12800
  float* h_out = out + 12800;                // 16384
  float* c_out = out + 12800 + 16384;        // 16384
  float* emb = out + 12800 + 16384 + 16384;  // 3,276,800

  // ---- workspace layout ----
  char* ws = (char*)d_ws;
  char* arena = ws;  // 186,646,528 B, phase-overlaid
  size_t o = 186646528;
  float* xbuf = (float*)(ws + o); o += 13107200;
  float* asrc = (float*)(ws + o); o += 409600;
  float* adst = (float*)(ws + o); o += 409600;
  float* gates = (float*)(ws + o); o += 262144;
  float* hq = (float*)(ws + o); o += 65536;
  float* ubuf = (float*)(ws + o); o += 51200;
  u16* xbufB = (u16*)(ws + o); o += 6553600;
  u16* embB = (u16*)(ws + o); o += 6553600;
  int* adjT = (int*)(ws + o); o += 10240000;
  unsigned* adjW = (unsigned*)(ws + o); o += 524288;
  u16* gatWT = (u16*)(ws + o); o += 2097152;
  u16* WqkvT = (u16*)(ws + o); o += 1179648;
  u16* WoT = (u16*)(ws + o); o += 393216;
  u16* W1T = (u16*)(ws + o); o += 786432;
  u16* W2T = (u16*)(ws + o); o += 786432;
  u16* WrefT = (u16*)(ws + o); o += 131072;
  if (ws_size < o) fprintf(stderr, "kernel_launch: ws too small (%zu < %zu)\n", ws_size, o);
  // GAT-phase arena views
  u16* xpB = (u16*)arena;                  // [BN][2048] bf16
  u16* xpT = (u16*)(arena + 52428800);     // [512][256][256] bf16
  u16* attnB = (u16*)(arena + 119537664);  // [512][256][256] bf16
  u16* encB = (u16*)(arena + 119537664);   // [BN][256] bf16 (dead before softmax)
  // encoder-phase arena views
  u16* qkvB = (u16*)arena;                 // [BN][768] bf16
  u16* ctxB = (u16*)(arena + 19660800);    // [BN][256] bf16
  u16* ffnB = (u16*)(arena + 26214400);    // [BN][512] bf16
  float* tmp = (float*)(arena + 39321600); // [BN][256] f32
  float* pref = (float*)arena;             // pointer phase

  // ---- prep ----
  prep_weights<<<dim3(512, 21), 256, 0, stream>>>(gat_W, enc_attn_W, enc_ffn_W1, enc_ffn_W2,
                                                  ptr_Wref, gatWT, WqkvT, WoT, W1T, W2T, WrefT);
  cast_bf16<<<3200, 256, 0, stream>>>(enc_inputs, encB, 819200);
  adj_transpose<<<dim3(7, 7, 64), 256, 0, stream>>>(adj, adjT);
  adj_bits<<<64, 256, 0, stream>>>(adj, adjW);

  // ---- GAT stack ----
  for (int g = 0; g < G_; ++g) {
    const u16* AinB = (g == 0) ? encB : xbufB;
    const float* xin = (g == 0) ? enc_inputs : xbuf;
    gemm_bf16<0, false, false, true><<<dim3(100, 16), 256, 0, stream>>>(
        AinB, gatWT + (size_t)g * 524288, nullptr, nullptr, nullptr, xpB, BN_, 2048, 256);
    gat_attvec<<<BN_, 256, 0, stream>>>(xpB, gat_att_src + g * 2048, gat_att_dst + g * 2048,
                                        asrc, adst);
    gat_attn_softmax<<<BN_ * NH_, 64, 0, stream>>>(asrc, adst, adjT, attnB);
    xp_transpose<<<dim3(8, 8, 512), 256, 0, stream>>>(xpB, xpT);
    gat_msg_mfma<<<dim3(2, 2, 64), 256, 0, stream>>>(attnB, xpT, gat_bias + g * H_, xin,
                                                     xbuf, xbufB);
  }
  ln_kernel<1><<<BN_, 256, 0, stream>>>(enc_inputs, xbuf, gat_ln, emb, embB);

  // ---- Transformer encoder ----
  for (int l = 0; l < L_; ++l) {
    gemm_bf16<0, true, false, true><<<dim3(100, 6), 256, 0, stream>>>(
        embB, WqkvT + (size_t)l * 196608, enc_attn_b + l * 1024, nullptr, nullptr, qkvB,
        BN_, 768, 256);
    attn_fused<<<512, 256, 0, stream>>>(qkvB, adjW, ctxB);
    gemm_bf16<0, true, true, false><<<dim3(100, 2), 256, 0, stream>>>(
        ctxB, WoT + (size_t)l * 65536, enc_attn_b + l * 1024 + 768, emb, tmp, nullptr,
        BN_, 256, 256);
    ln_kernel<0><<<BN_, 256, 0, stream>>>(tmp, nullptr, enc_ln1 + l * 512, emb, embB);
    gemm_bf16<1, true, false, true><<<dim3(100, 4), 256, 0, stream>>>(
        embB, W1T + (size_t)l * 131072, enc_ffn_b1 + l * 512, nullptr, nullptr, ffnB,
        BN_, 512, 256);
    gemm_bf16<0, true, true, false><<<dim3(100, 2), 256, 0, stream>>>(
        ffnB, W2T + (size_t)l * 131072, enc_ffn_b2 + l * 256, emb, tmp, nullptr,
        BN_, 256, 512);
    ln_kernel<0><<<BN_, 256, 0, stream>>>(tmp, nullptr, enc_ln2 + l * 512, emb, embB);
  }

  // ---- LSTM + pointer ----
  lstm_gates<<<256, 256, 0, stream>>>(dec_input, dec_h, lstm_Wih, lstm_Whh, lstm_b, gates);
  lstm_ew<<<64, 256, 0, stream>>>(gates, dec_c, h_out, c_out);
  hq_gemm<<<64, 256, 0, stream>>>(h_out, ptr_Wq, hq);
  gemm_bf16<0, false, false, false><<<dim3(100, 2), 256, 0, stream>>>(
      embB, WrefT, nullptr, nullptr, pref, nullptr, BN_, 256, 256);
  ptr_u<<<BN_, 64, 0, stream>>>(pref, hq, ptr_v, ubuf);
  policy_softmax<<<B_, 256, 0, stream>>>(ubuf, mask, policy);
}

// Round 6
// 800.090 us; speedup vs baseline: 5.5593x; 1.0684x over previous
//
#include <hip/hip_runtime.h>
#include <cstdio>
#include <math.h>

static constexpr int B_ = 64, N_ = 200, H_ = 256, NH_ = 8, G_ = 2, L_ = 3, F_ = 512;
static constexpr int BN_ = B_ * N_;  // 12800

typedef unsigned short u16;
typedef __attribute__((ext_vector_type(8))) short short8;
typedef __attribute__((ext_vector_type(4))) float f32x4;

#define LDSP(p) ((__attribute__((address_space(3))) unsigned int*)(p))
#define GLBP(p) ((const __attribute__((address_space(1))) unsigned int*)(p))

__device__ __forceinline__ float wave_sum64(float v) {
#pragma unroll
  for (int off = 32; off; off >>= 1) v += __shfl_xor(v, off);
  return v;
}
__device__ __forceinline__ float wave_max64(float v) {
#pragma unroll
  for (int off = 32; off; off >>= 1) v = fmaxf(v, __shfl_xor(v, off));
  return v;
}
__device__ __forceinline__ float sigmoidf_(float x) { return 1.f / (1.f + __expf(-x)); }
__device__ __forceinline__ u16 f2bf(float x) {  // RNE f32->bf16
  unsigned u = __float_as_uint(x);
  return (u16)((u + 0x7FFFu + ((u >> 16) & 1u)) >> 16);
}
__device__ __forceinline__ float bf2f(u16 x) { return __uint_as_float((unsigned)x << 16); }

// ================= bf16 MFMA GEMM =================
// C[M][Nn] = act(A @ Bt^T + bias + res). A: bf16 [M][K]; Bt: bf16 [Nn][K].
// Tile 128x128, BK=64, 4 waves (2x2 of 64x64). K%64==0, M%128==0, Nn%128==0.
template <int ACT, bool HAS_BIAS, bool HAS_RES, bool OUT_BF>
__global__ __launch_bounds__(256) void gemm_bf16(
    const u16* __restrict__ A, const u16* __restrict__ Bt,
    const float* __restrict__ bias, const float* __restrict__ res,
    float* __restrict__ Cf, u16* __restrict__ Cb, int M, int Nn, int K) {
  __shared__ u16 As[128 * 64];
  __shared__ u16 Bs[128 * 64];
  char* asB = (char*)As;
  char* bsB = (char*)Bs;
  const int tid = threadIdx.x;
  const int m0 = blockIdx.x * 128, n0 = blockIdx.y * 128;
  const int lane = tid & 63;
  const int wid = tid >> 6;
  const int wr = (wid >> 1) * 64, wc = (wid & 1) * 64;
  const int Kb = K * 2;
  const char* Ab = (const char*)A + (size_t)m0 * Kb;
  const char* Bb = (const char*)Bt + (size_t)n0 * Kb;
  f32x4 acc[4][4];
#pragma unroll
  for (int i = 0; i < 4; ++i)
#pragma unroll
    for (int j = 0; j < 4; ++j)
#pragma unroll
      for (int r = 0; r < 4; ++r) acc[i][j][r] = 0.f;

  for (int k0 = 0; k0 < K; k0 += 64) {
    if (k0) __syncthreads();
#pragma unroll
    for (int it = 0; it < 4; ++it) {
      const unsigned o = (unsigned)(it * 256 + tid) * 16;  // linear LDS byte offset
      const int row = o >> 7;
      const unsigned bc = (o & 127u) ^ (unsigned)((row & 7) << 4);  // inverse-swizzled src col
      const unsigned wb = o & ~1023u;  // wave-uniform LDS base
      __builtin_amdgcn_global_load_lds(GLBP(Ab + (size_t)row * Kb + k0 * 2 + bc),
                                       LDSP(asB + wb), 16, 0, 0);
      __builtin_amdgcn_global_load_lds(GLBP(Bb + (size_t)row * Kb + k0 * 2 + bc),
                                       LDSP(bsB + wb), 16, 0, 0);
    }
    __syncthreads();
#pragma unroll
    for (int kk = 0; kk < 2; ++kk) {
      short8 aF[4], bF[4];
#pragma unroll
      for (int i = 0; i < 4; ++i) {
        const int ar = wr + i * 16 + (lane & 15);
        const unsigned ac = (unsigned)(kk * 64 + (lane >> 4) * 16) ^ (unsigned)((ar & 7) << 4);
        aF[i] = *(const short8*)(asB + ar * 128 + ac);
        const int br = wc + i * 16 + (lane & 15);
        const unsigned bc2 = (unsigned)(kk * 64 + (lane >> 4) * 16) ^ (unsigned)((br & 7) << 4);
        bF[i] = *(const short8*)(bsB + br * 128 + bc2);
      }
#pragma unroll
      for (int i = 0; i < 4; ++i)
#pragma unroll
        for (int j = 0; j < 4; ++j)
          acc[i][j] = __builtin_amdgcn_mfma_f32_16x16x32_bf16(aF[i], bF[j], acc[i][j], 0, 0, 0);
    }
  }
  // epilogue: C/D layout col=lane&15, row=(lane>>4)*4+reg  [m89]
#pragma unroll
  for (int i = 0; i < 4; ++i) {
    const int gm0 = m0 + wr + i * 16 + (lane >> 4) * 4;
#pragma unroll
    for (int j = 0; j < 4; ++j) {
      const int gn = n0 + wc + j * 16 + (lane & 15);
      const float bv = HAS_BIAS ? bias[gn] : 0.f;
#pragma unroll
      for (int r = 0; r < 4; ++r) {
        const int gm = gm0 + r;
        float v = acc[i][j][r] + bv;
        if (HAS_RES) v += res[(size_t)gm * Nn + gn];
        if (ACT == 1) v = fmaxf(v, 0.f);
        if (OUT_BF)
          Cb[(size_t)gm * Nn + gn] = f2bf(v);
        else
          Cf[(size_t)gm * Nn + gn] = v;
      }
    }
  }
}

// ================= GAT projection -> transposed slabs =================
// xpT[b][h][d][i] = sum_k gatWT[h*256+d][k] * actB[b*200+i][k]; zero for i>=200.
// grid (16, 2, 64), 256 thr. actB over-read past b slab is harmless (allocated).
__global__ __launch_bounds__(256) void gat_projT(
    const u16* __restrict__ Wt, const u16* __restrict__ actB, u16* __restrict__ xpT) {
  __shared__ u16 As[128 * 64];
  __shared__ u16 Bs[128 * 64];
  char* asB = (char*)As;
  char* bsB = (char*)Bs;
  const int tid = threadIdx.x;
  const int m0 = blockIdx.x * 128;  // hd row
  const int n0 = blockIdx.y * 128;  // i col
  const int b = blockIdx.z;
  const int lane = tid & 63;
  const int wid = tid >> 6;
  const int wr = (wid >> 1) * 64, wc = (wid & 1) * 64;
  const char* Ab = (const char*)Wt + (size_t)m0 * 512;
  const char* Bb = (const char*)actB + ((size_t)b * 200 + n0) * 512;
  f32x4 acc[4][4];
#pragma unroll
  for (int i = 0; i < 4; ++i)
#pragma unroll
    for (int j = 0; j < 4; ++j)
#pragma unroll
      for (int r = 0; r < 4; ++r) acc[i][j][r] = 0.f;

  for (int k0 = 0; k0 < 256; k0 += 64) {
    if (k0) __syncthreads();
#pragma unroll
    for (int it = 0; it < 4; ++it) {
      const unsigned o = (unsigned)(it * 256 + tid) * 16;
      const int row = o >> 7;
      const unsigned bc = (o & 127u) ^ (unsigned)((row & 7) << 4);
      const unsigned wb = o & ~1023u;
      __builtin_amdgcn_global_load_lds(GLBP(Ab + (size_t)row * 512 + k0 * 2 + bc),
                                       LDSP(asB + wb), 16, 0, 0);
      __builtin_amdgcn_global_load_lds(GLBP(Bb + (size_t)row * 512 + k0 * 2 + bc),
                                       LDSP(bsB + wb), 16, 0, 0);
    }
    __syncthreads();
#pragma unroll
    for (int kk = 0; kk < 2; ++kk) {
      short8 aF[4], bF[4];
#pragma unroll
      for (int i = 0; i < 4; ++i) {
        const int ar = wr + i * 16 + (lane & 15);
        const unsigned ac = (unsigned)(kk * 64 + (lane >> 4) * 16) ^ (unsigned)((ar & 7) << 4);
        aF[i] = *(const short8*)(asB + ar * 128 + ac);
        const int br = wc + i * 16 + (lane & 15);
        const unsigned bc2 = (unsigned)(kk * 64 + (lane >> 4) * 16) ^ (unsigned)((br & 7) << 4);
        bF[i] = *(const short8*)(bsB + br * 128 + bc2);
      }
#pragma unroll
      for (int i = 0; i < 4; ++i)
#pragma unroll
        for (int j = 0; j < 4; ++j)
          acc[i][j] = __builtin_amdgcn_mfma_f32_16x16x32_bf16(aF[i], bF[j], acc[i][j], 0, 0, 0);
    }
  }
  u16* outb = xpT + (size_t)b * 524288;
#pragma unroll
  for (int i = 0; i < 4; ++i) {
    const int gm0 = m0 + wr + i * 16 + (lane >> 4) * 4;
#pragma unroll
    for (int j = 0; j < 4; ++j) {
      const int gn = n0 + wc + j * 16 + (lane & 15);
#pragma unroll
      for (int r = 0; r < 4; ++r) {
        const int gm = gm0 + r;
        outb[(size_t)gm * 256 + gn] = (gn < N_) ? f2bf(acc[i][j][r]) : (u16)0;
      }
    }
  }
}

// ================= GAT message MFMA (2-phase double-buffered) =================
// out[b,j,d] = xin[b,j,d] + relu( (1/8) sum_{h,i} attnB[b,h,j,i]*xpT[b,h,d,i] + bias[d] )
__global__ __launch_bounds__(256) void gat_msg_mfma(
    const u16* __restrict__ attnB, const u16* __restrict__ xpT,
    const float* __restrict__ bias, const float* __restrict__ xin,
    float* __restrict__ xout, u16* __restrict__ xoutB) {
  __shared__ u16 As[2][128 * 64];
  __shared__ u16 Bs[2][128 * 64];
  const int tid = threadIdx.x;
  const int m0 = blockIdx.x * 128, n0 = blockIdx.y * 128;
  const int b = blockIdx.z;
  const int lane = tid & 63, wid = tid >> 6;
  const int wr = (wid >> 1) * 64, wc = (wid & 1) * 64;
  const char* baseA = (const char*)attnB + ((size_t)b << 20) + (size_t)m0 * 512;
  const char* baseB = (const char*)xpT + ((size_t)b << 20) + (size_t)n0 * 512;
  f32x4 acc[4][4];
#pragma unroll
  for (int i = 0; i < 4; ++i)
#pragma unroll
    for (int j = 0; j < 4; ++j)
#pragma unroll
      for (int r = 0; r < 4; ++r) acc[i][j][r] = 0.f;

  auto stage = [&](int buf, int t) {
    const size_t off = (size_t)(t >> 2) * 131072 + (size_t)((t & 3) * 128);
    char* aD = (char*)As + buf * 16384;
    char* bD = (char*)Bs + buf * 16384;
#pragma unroll
    for (int it = 0; it < 4; ++it) {
      const unsigned o = (unsigned)(it * 256 + tid) * 16;
      const int row = o >> 7;
      const unsigned bc = (o & 127u) ^ (unsigned)((row & 7) << 4);
      const unsigned wb = o & ~1023u;
      __builtin_amdgcn_global_load_lds(GLBP(baseA + off + (size_t)row * 512 + bc),
                                       LDSP(aD + wb), 16, 0, 0);
      __builtin_amdgcn_global_load_lds(GLBP(baseB + off + (size_t)row * 512 + bc),
                                       LDSP(bD + wb), 16, 0, 0);
    }
  };

  stage(0, 0);
  asm volatile("s_waitcnt vmcnt(0)" ::: "memory");
  __builtin_amdgcn_s_barrier();
  int cur = 0;
  for (int t = 0; t < 32; ++t) {
    if (t + 1 < 32) stage(cur ^ 1, t + 1);
    const char* asB = (const char*)As + cur * 16384;
    const char* bsB = (const char*)Bs + cur * 16384;
#pragma unroll
    for (int kk = 0; kk < 2; ++kk) {
      short8 aF[4], bF[4];
#pragma unroll
      for (int i = 0; i < 4; ++i) {
        const int ar = wr + i * 16 + (lane & 15);
        const unsigned ac = (unsigned)(kk * 64 + (lane >> 4) * 16) ^ (unsigned)((ar & 7) << 4);
        aF[i] = *(const short8*)(asB + ar * 128 + ac);
        const int br = wc + i * 16 + (lane & 15);
        const unsigned bc2 = (unsigned)(kk * 64 + (lane >> 4) * 16) ^ (unsigned)((br & 7) << 4);
        bF[i] = *(const short8*)(bsB + br * 128 + bc2);
      }
#pragma unroll
      for (int i = 0; i < 4; ++i)
#pragma unroll
        for (int j = 0; j < 4; ++j)
          acc[i][j] = __builtin_amdgcn_mfma_f32_16x16x32_bf16(aF[i], bF[j], acc[i][j], 0, 0, 0);
    }
    asm volatile("s_waitcnt vmcnt(0)" ::: "memory");
    __builtin_amdgcn_s_barrier();
    cur ^= 1;
  }
#pragma unroll
  for (int i = 0; i < 4; ++i) {
    const int gm0 = m0 + wr + i * 16 + (lane >> 4) * 4;
#pragma unroll
    for (int j = 0; j < 4; ++j) {
      const int gn = n0 + wc + j * 16 + (lane & 15);
      const float bv = bias[gn];
#pragma unroll
      for (int r = 0; r < 4; ++r) {
        const int gm = gm0 + r;
        if (gm < N_) {
          const size_t oo = (size_t)(b * N_ + gm) * 256 + gn;
          const float v = xin[oo] + fmaxf(acc[i][j][r] * 0.125f + bv, 0.f);
          xout[oo] = v;
          xoutB[oo] = f2bf(v);
        }
      }
    }
  }
}

// ================= fused encoder attention =================
// grid 512 = b*8+h, 256 thr (4 waves). ctx[b,q,h*32+d] = softmax(mask(QK^T/sqrt32)) @ V
__global__ __launch_bounds__(256) void attn_fused(
    const u16* __restrict__ qkvB, const unsigned* __restrict__ adjW,
    u16* __restrict__ ctxB) {
  __shared__ __align__(16) u16 K_lds[208 * 40];    // [kv][40] stride 80B
  __shared__ __align__(16) u16 V_lds[32 * 232];    // [d][232] stride 464B (V^T)
  __shared__ __align__(16) u16 P_lds[4][16 * 232]; // per-wave [16 q][232 kv]
  const int bh = blockIdx.x;
  const int b = bh >> 3, h = bh & 7;
  const int tid = threadIdx.x, lane = tid & 63, wid = tid >> 6;
  const u16* qb = qkvB + (size_t)b * 200 * 768;
  // stage K rows + V transposed
  for (int e = tid; e < 200 * 32; e += 256) {
    const int kv = e >> 5, d = e & 31;
    K_lds[kv * 40 + d] = qb[(size_t)kv * 768 + 256 + h * 32 + d];
    V_lds[d * 232 + kv] = qb[(size_t)kv * 768 + 512 + h * 32 + d];
  }
  // zero V pad rows kv 200..223 (avoid NaN poison: P_pad(0) * V_garbage)
  for (int e = tid; e < 32 * 24; e += 256) V_lds[(e / 24) * 232 + 200 + (e % 24)] = 0;
  const int g = lane >> 4, c = lane & 15;
  u16* Pw = P_lds[wid];
  // zero P pad cols 208..223 for this wave
  for (int e = lane; e < 16 * 16; e += 64) Pw[(e >> 4) * 232 + 208 + (e & 15)] = 0;
  __syncthreads();
  // cache K fragments (13 n-tiles)
  short8 kf[13];
#pragma unroll
  for (int nt = 0; nt < 13; ++nt)
    kf[nt] = *(const short8*)&K_lds[(nt * 16 + c) * 40 + g * 8];
  const float scale = 0.17677669529663687f;  // 1/sqrt(32)
  for (int t = 0; t < 4; ++t) {
    const int m0 = (wid * 4 + t) * 16;
    // Q fragment from global (row-clamped; garbage rows stay in garbage outputs)
    int qrow = b * 200 + m0 + c;
    if (qrow > BN_ - 1) qrow = BN_ - 1;
    const short8 qf = *(const short8*)&qkvB[(size_t)qrow * 768 + h * 32 + g * 8];
    // S = Q@K^T
    f32x4 acc[13];
#pragma unroll
    for (int nt = 0; nt < 13; ++nt) {
      f32x4 z = {0.f, 0.f, 0.f, 0.f};
      acc[nt] = __builtin_amdgcn_mfma_f32_16x16x32_bf16(qf, kf[nt], z, 0, 0, 0);
    }
    // adj bitmask for this lane-group's 4 rows
    unsigned m8[4][8];
#pragma unroll
    for (int r = 0; r < 4; ++r) {
      const uint4* mp = (const uint4*)(adjW + ((size_t)b * 256 + m0 + g * 4 + r) * 8);
      const uint4 a0 = mp[0], a1 = mp[1];
      m8[r][0] = a0.x; m8[r][1] = a0.y; m8[r][2] = a0.z; m8[r][3] = a0.w;
      m8[r][4] = a1.x; m8[r][5] = a1.y; m8[r][6] = a1.z; m8[r][7] = a1.w;
    }
    // mask + scale
    float mx[4] = {-3e38f, -3e38f, -3e38f, -3e38f};
#pragma unroll
    for (int nt = 0; nt < 13; ++nt) {
      const int col = nt * 16 + c;
      const float sentinel = (col < 200) ? -1e9f : -2e9f;
#pragma unroll
      for (int r = 0; r < 4; ++r) {
        const bool ok = (m8[r][nt >> 1] >> (((nt & 1) << 4) + c)) & 1u;
        const float v = ok ? acc[nt][r] * scale : sentinel;
        acc[nt][r] = v;
        mx[r] = fmaxf(mx[r], v);
      }
    }
    // row reduce max over 16-lane group
#pragma unroll
    for (int off = 1; off < 16; off <<= 1)
#pragma unroll
      for (int r = 0; r < 4; ++r) mx[r] = fmaxf(mx[r], __shfl_xor(mx[r], off));
    // exp + sum
    float sm[4] = {0.f, 0.f, 0.f, 0.f};
#pragma unroll
    for (int nt = 0; nt < 13; ++nt)
#pragma unroll
      for (int r = 0; r < 4; ++r) {
        const float e = __expf(acc[nt][r] - mx[r]);
        acc[nt][r] = e;
        sm[r] += e;
      }
#pragma unroll
    for (int off = 1; off < 16; off <<= 1)
#pragma unroll
      for (int r = 0; r < 4; ++r) sm[r] += __shfl_xor(sm[r], off);
#pragma unroll
    for (int r = 0; r < 4; ++r) sm[r] = 1.f / sm[r];
    // P -> per-wave LDS (bf16)
#pragma unroll
    for (int nt = 0; nt < 13; ++nt)
#pragma unroll
      for (int r = 0; r < 4; ++r)
        Pw[(g * 4 + r) * 232 + nt * 16 + c] = f2bf(acc[nt][r] * sm[r]);
    // ctx = P @ V  (K=224, 7 k-tiles; d-tiles 2)
    f32x4 o0 = {0.f, 0.f, 0.f, 0.f}, o1 = {0.f, 0.f, 0.f, 0.f};
#pragma unroll
    for (int kt = 0; kt < 7; ++kt) {
      const short8 pf = *(const short8*)&Pw[c * 232 + kt * 32 + g * 8];
      const short8 v0 = *(const short8*)&V_lds[c * 232 + kt * 32 + g * 8];
      const short8 v1 = *(const short8*)&V_lds[(16 + c) * 232 + kt * 32 + g * 8];
      o0 = __builtin_amdgcn_mfma_f32_16x16x32_bf16(pf, v0, o0, 0, 0, 0);
      o1 = __builtin_amdgcn_mfma_f32_16x16x32_bf16(pf, v1, o1, 0, 0, 0);
    }
#pragma unroll
    for (int r = 0; r < 4; ++r) {
      const int q = m0 + g * 4 + r;
      if (q < N_) {
        u16* od = ctxB + ((size_t)(b * N_ + q)) * 256 + h * 32;
        od[c] = f2bf(o0[r]);
        od[16 + c] = f2bf(o1[r]);
      }
    }
  }
}

// adjW[b][row][w] = bitmask of adj[b][row][w*32..] > 0 (rows>=200, w==7 -> 0)
__global__ __launch_bounds__(256) void adj_bits(const int* __restrict__ adj,
                                                unsigned* __restrict__ adjW) {
  const int b = blockIdx.x;
  for (int e = threadIdx.x; e < 256 * 8; e += 256) {
    const int row = e >> 3, w = e & 7;
    unsigned bits = 0u;
    if (row < N_ && w < 7) {
      const int base = w * 32;
      const int lim = (N_ - base) < 32 ? (N_ - base) : 32;
      const int* ar = adj + ((size_t)b * N_ + row) * N_ + base;
      for (int i = 0; i < lim; ++i) bits |= (ar[i] > 0 ? 1u : 0u) << i;
    }
    adjW[((size_t)b * 256 + row) * 8 + w] = bits;
  }
}

// ================= adj transpose =================
__global__ __launch_bounds__(256) void adj_transpose(const int* __restrict__ adj,
                                                     int* __restrict__ adjT) {
  __shared__ int s[32][33];
  const int b = blockIdx.z;
  const int i0 = blockIdx.x * 32, j0 = blockIdx.y * 32;
  const int tx = threadIdx.x & 31, ty = threadIdx.x >> 5;
#pragma unroll
  for (int u = 0; u < 4; ++u) {
    const int i = i0 + ty + 8 * u, j = j0 + tx;
    if (i < N_ && j < N_) s[ty + 8 * u][tx] = adj[((size_t)b * N_ + i) * N_ + j];
  }
  __syncthreads();
#pragma unroll
  for (int u = 0; u < 4; ++u) {
    const int j = j0 + ty + 8 * u, i = i0 + tx;
    if (i < N_ && j < N_) adjT[((size_t)b * N_ + j) * N_ + i] = s[tx][ty + 8 * u];
  }
}

// ================= weight prep =================
__device__ const int PREP_TBL[21][6] = {
    {0, 0, 0, 0, 256, 2048},
    {0, 524288, 0, 524288, 256, 2048},
    {1, 0 * 65536, 1, 0, 256, 256},      {1, 1 * 65536, 1, 65536, 256, 256},
    {1, 2 * 65536, 1, 131072, 256, 256}, {1, 4 * 65536, 1, 196608, 256, 256},
    {1, 5 * 65536, 1, 262144, 256, 256}, {1, 6 * 65536, 1, 327680, 256, 256},
    {1, 8 * 65536, 1, 393216, 256, 256}, {1, 9 * 65536, 1, 458752, 256, 256},
    {1, 10 * 65536, 1, 524288, 256, 256},
    {1, 3 * 65536, 2, 0, 256, 256},      {1, 7 * 65536, 2, 65536, 256, 256},
    {1, 11 * 65536, 2, 131072, 256, 256},
    {2, 0, 3, 0, 256, 512}, {2, 131072, 3, 131072, 256, 512}, {2, 262144, 3, 262144, 256, 512},
    {3, 0, 4, 0, 512, 256}, {3, 131072, 4, 131072, 512, 256}, {3, 262144, 4, 262144, 512, 256},
    {4, 0, 5, 0, 256, 256},
};

__global__ __launch_bounds__(256) void prep_weights(
    const float* __restrict__ gat_W, const float* __restrict__ attn_W,
    const float* __restrict__ W1, const float* __restrict__ W2,
    const float* __restrict__ Wref, u16* __restrict__ gatWT, u16* __restrict__ WqkvT,
    u16* __restrict__ WoT, u16* __restrict__ W1T, u16* __restrict__ W2T,
    u16* __restrict__ WrefT) {
  const int mi = blockIdx.y;
  const int R = PREP_TBL[mi][4], C = PREP_TBL[mi][5];
  const int tc = C / 32;
  const int tiles = (R / 32) * tc;
  if ((int)blockIdx.x >= tiles) return;
  const int sel = PREP_TBL[mi][0], dsel = PREP_TBL[mi][2];
  const float* sp = (sel == 0) ? gat_W : (sel == 1) ? attn_W : (sel == 2) ? W1 : (sel == 3) ? W2 : Wref;
  u16* dp = (dsel == 0) ? gatWT : (dsel == 1) ? WqkvT : (dsel == 2) ? WoT : (dsel == 3) ? W1T
            : (dsel == 4) ? W2T : WrefT;
  sp += PREP_TBL[mi][1];
  dp += PREP_TBL[mi][3];
  const int r0 = (blockIdx.x / tc) * 32, c0 = (blockIdx.x % tc) * 32;
  __shared__ float s[32][33];
  const int tx = threadIdx.x & 31, ty = threadIdx.x >> 5;
#pragma unroll
  for (int u = 0; u < 4; ++u) s[ty + 8 * u][tx] = sp[(size_t)(r0 + ty + 8 * u) * C + c0 + tx];
  __syncthreads();
#pragma unroll
  for (int u = 0; u < 4; ++u)
    dp[(size_t)(c0 + ty + 8 * u) * R + r0 + tx] = f2bf(s[tx][ty + 8 * u]);
}

__global__ __launch_bounds__(256) void cast_bf16(const float* __restrict__ in,
                                                 u16* __restrict__ out, int n4) {
  const int i = blockIdx.x * 256 + threadIdx.x;
  if (i >= n4) return;
  const float4 v = ((const float4*)in)[i];
  ushort4 o;
  o.x = f2bf(v.x); o.y = f2bf(v.y); o.z = f2bf(v.z); o.w = f2bf(v.w);
  ((ushort4*)out)[i] = o;
}

// ================= GAT attention =================
// one block per (b,h); thread = source node i; reads xpT slab columns (coalesced over i)
__global__ __launch_bounds__(256) void gat_attvec(
    const u16* __restrict__ xpT, const float* __restrict__ att_src,
    const float* __restrict__ att_dst, float* __restrict__ a_src,
    float* __restrict__ a_dst) {
  const int bh = blockIdx.x;
  const int b = bh >> 3, h = bh & 7;
  const int i = threadIdx.x;
  const u16* base = xpT + (size_t)bh * 65536 + i;
  const float* vs = att_src + h * 256;
  const float* vd = att_dst + h * 256;
  float ps = 0.f, pd = 0.f;
  for (int d = 0; d < 256; ++d) {
    const float x = bf2f(base[(size_t)d * 256]);
    ps += x * vs[d];
    pd += x * vd[d];
  }
  if (i < N_) {
    a_src[(b * N_ + i) * 8 + h] = ps;
    a_dst[(b * N_ + i) * 8 + h] = pd;
  }
}

__global__ __launch_bounds__(64) void gat_attn_softmax(
    const float* __restrict__ a_src, const float* __restrict__ a_dst,
    const int* __restrict__ adjT, u16* __restrict__ attnB) {
  const int id = blockIdx.x;
  const int h = id & 7;
  const int bj = id >> 3;
  const int j = bj % N_, b = bj / N_;
  const float ad = a_dst[bj * 8 + h];
  const int lane = threadIdx.x;
  const int* arow = adjT + ((size_t)b * N_ + j) * N_;
  float vals[4];
  float mx = -1e30f;
#pragma unroll
  for (int r = 0; r < 4; ++r) {
    const int i = lane + r * 64;
    float v = -1e30f;
    if (i < N_) {
      float x = ad + a_src[(b * N_ + i) * 8 + h];
      x = x > 0.f ? x : 0.2f * x;
      const bool ok = (i == j) || (arow[i] > 0);
      v = ok ? x : -1e9f;
    }
    vals[r] = v;
    mx = fmaxf(mx, v);
  }
  mx = wave_max64(mx);
  float sum = 0.f;
#pragma unroll
  for (int r = 0; r < 4; ++r) {
    const int i = lane + r * 64;
    if (i < N_) {
      const float e = __expf(vals[r] - mx);
      vals[r] = e;
      sum += e;
    }
  }
  sum = wave_sum64(sum);
  const float inv = 1.f / sum;
  u16* row = attnB + ((size_t)(b * 8 + h) * 256 + j) * 256;
#pragma unroll
  for (int r = 0; r < 4; ++r) {
    const int i = lane + r * 64;
    row[i] = (i < N_) ? f2bf(vals[r] * inv) : (u16)0;
  }
}

// ================= LayerNorm (dual f32 + bf16 out) =================
template <int PRE>
__global__ __launch_bounds__(256) void ln_kernel(
    const float* __restrict__ in1, const float* __restrict__ in2,
    const float* __restrict__ sb, float* __restrict__ out, u16* __restrict__ outB) {
  const int row = blockIdx.x, t = threadIdx.x;
  const long o = (long)row * 256 + t;
  const float v = PRE ? (in1[o] + fmaxf(in2[o], 0.f)) : in1[o];
  float s = v, q = v * v;
#pragma unroll
  for (int off = 32; off; off >>= 1) {
    s += __shfl_xor(s, off);
    q += __shfl_xor(q, off);
  }
  __shared__ float sh[8];
  const int wid = t >> 6, lane = t & 63;
  if (lane == 0) {
    sh[wid] = s;
    sh[4 + wid] = q;
  }
  __syncthreads();
  const float S = sh[0] + sh[1] + sh[2] + sh[3];
  const float Q = sh[4] + sh[5] + sh[6] + sh[7];
  const float mean = S * (1.f / 256.f);
  const float var = Q * (1.f / 256.f) - mean * mean;
  const float r = rsqrtf(var + 1e-5f);
  const float y = (v - mean) * r * sb[t] + sb[256 + t];
  out[o] = y;
  outB[o] = f2bf(y);
}

// ================= LSTM + pointer =================
__global__ __launch_bounds__(256) void lstm_gates(
    const float* __restrict__ di, const float* __restrict__ dh,
    const float* __restrict__ Wih, const float* __restrict__ Whh,
    const float* __restrict__ bias, float* __restrict__ gates) {
  const int idx = blockIdx.x * 256 + threadIdx.x;
  const int b = idx >> 10, n = idx & 1023;
  const float* w1 = Wih + (long)n * 256;
  const float* w2 = Whh + (long)n * 256;
  const float* x1 = di + b * 256;
  const float* x2 = dh + b * 256;
  float s = bias[n];
  for (int k = 0; k < 256; ++k) s += x1[k] * w1[k] + x2[k] * w2[k];
  gates[idx] = s;
}

__global__ __launch_bounds__(256) void lstm_ew(
    const float* __restrict__ gates, const float* __restrict__ dc,
    float* __restrict__ h_out, float* __restrict__ c_out) {
  const int idx = blockIdx.x * 256 + threadIdx.x;
  const int b = idx >> 8, d = idx & 255;
  const float ig = sigmoidf_(gates[b * 1024 + d]);
  const float fg = sigmoidf_(gates[b * 1024 + 256 + d]);
  const float gg = tanhf(gates[b * 1024 + 512 + d]);
  const float og = sigmoidf_(gates[b * 1024 + 768 + d]);
  const float c = fg * dc[idx] + ig * gg;
  c_out[idx] = c;
  h_out[idx] = og * tanhf(c);
}

__global__ __launch_bounds__(256) void hq_gemm(
    const float* __restrict__ h, const float* __restrict__ Wq, float* __restrict__ hq) {
  const int b = blockIdx.x;
  const int n = threadIdx.x;
  float s = 0.f;
  for (int k = 0; k < 256; ++k) s += h[b * 256 + k] * Wq[k * 256 + n];
  hq[b * 256 + n] = s;
}

__global__ __launch_bounds__(64) void ptr_u(
    const float* __restrict__ pref, const float* __restrict__ hq,
    const float* __restrict__ pv, float* __restrict__ u) {
  const int row = blockIdx.x;
  const int b = row / N_;
  const int lane = threadIdx.x;
  float s = 0.f;
  for (int d = lane; d < 256; d += 64)
    s += tanhf(pref[(long)row * 256 + d] + hq[b * 256 + d]) * pv[d];
  s = wave_sum64(s);
  if (lane == 0) u[row] = s;
}

__global__ __launch_bounds__(256) void policy_softmax(
    const float* __restrict__ u, const int* __restrict__ mask, float* __restrict__ pol) {
  const int b = blockIdx.x, t = threadIdx.x;
  float val = -1e30f;
  if (t < N_) val = (mask[b * N_ + t] > 0) ? u[b * N_ + t] : -1e9f;
  float m = val;
#pragma unroll
  for (int off = 32; off; off >>= 1) m = fmaxf(m, __shfl_xor(m, off));
  __shared__ float sh[8];
  const int wid = t >> 6, lane = t & 63;
  if (lane == 0) sh[wid] = m;
  __syncthreads();
  m = fmaxf(fmaxf(sh[0], sh[1]), fmaxf(sh[2], sh[3]));
  const float e = (t < N_) ? __expf(val - m) : 0.f;
  float s = e;
#pragma unroll
  for (int off = 32; off; off >>= 1) s += __shfl_xor(s, off);
  __syncthreads();
  if (lane == 0) sh[4 + wid] = s;
  __syncthreads();
  const float S = sh[4] + sh[5] + sh[6] + sh[7];
  if (t < N_) pol[b * N_ + t] = e / S;
}

extern "C" void kernel_launch(void* const* d_in, const int* in_sizes, int n_in,
                              void* d_out, int out_size, void* d_ws, size_t ws_size,
                              hipStream_t stream) {
  const float* enc_inputs = (const float*)d_in[0];
  const float* dec_input = (const float*)d_in[1];
  const float* dec_h = (const float*)d_in[2];
  const float* dec_c = (const float*)d_in[3];
  const float* gat_W = (const float*)d_in[4];
  const float* gat_att_src = (const float*)d_in[5];
  const float* gat_att_dst = (const float*)d_in[6];
  const float* gat_bias = (const float*)d_in[7];
  const float* gat_ln = (const float*)d_in[8];
  const float* enc_attn_W = (const float*)d_in[9];
  const float* enc_attn_b = (const float*)d_in[10];
  const float* enc_ln1 = (const float*)d_in[11];
  const float* enc_ffn_W1 = (const float*)d_in[12];
  const float* enc_ffn_b1 = (const float*)d_in[13];
  const float* enc_ffn_W2 = (const float*)d_in[14];
  const float* enc_ffn_b2 = (const float*)d_in[15];
  const float* enc_ln2 = (const float*)d_in[16];
  const float* lstm_Wih = (const float*)d_in[17];
  const float* lstm_Whh = (const float*)d_in[18];
  const float* lstm_b = (const float*)d_in[19];
  const float* ptr_Wref = (const float*)d_in[20];
  const float* ptr_Wq = (const float*)d_in[21];
  const float* ptr_v = (const float*)d_in[22];
  const int* adj = (const int*)d_in[23];
  const int* mask = (const int*)d_in[24];

  float* out = (float*)d_out;
  float* policy = out;                       // 12800
  float* h_out = out + 12800;                // 16384
  float* c_out = out + 12800 + 16384;        // 16384
  float* emb = out + 12800 + 16384 + 16384;  // 3,276,800

  // ---- workspace layout ----
  char* ws = (char*)d_ws;
  char* arena = ws;  // 134,217,728 B phase-overlaid (GAT: xpT+attnB; encoder: qkv etc.)
  size_t o = 134217728;
  float* xbuf = (float*)(ws + o); o += 13107200;
  float* asrc = (float*)(ws + o); o += 409600;
  float* adst = (float*)(ws + o); o += 409600;
  float* gates = (float*)(ws + o); o += 262144;
  float* hq = (float*)(ws + o); o += 65536;
  float* ubuf = (float*)(ws + o); o += 51200;
  u16* encB = (u16*)(ws + o); o += 6553600;
  u16* xbufB = (u16*)(ws + o); o += 6553600;
  u16* embB = (u16*)(ws + o); o += 6553600;
  int* adjT = (int*)(ws + o); o += 10240000;
  unsigned* adjW = (unsigned*)(ws + o); o += 524288;
  u16* gatWT = (u16*)(ws + o); o += 2097152;
  u16* WqkvT = (u16*)(ws + o); o += 1179648;
  u16* WoT = (u16*)(ws + o); o += 393216;
  u16* W1T = (u16*)(ws + o); o += 786432;
  u16* W2T = (u16*)(ws + o); o += 786432;
  u16* WrefT = (u16*)(ws + o); o += 131072;
  if (ws_size < o) fprintf(stderr, "kernel_launch: ws too small (%zu < %zu)\n", ws_size, o);
  // GAT-phase arena views
  u16* xpT = (u16*)arena;                  // [B][8][256][256] bf16 (67,108,864 B)
  u16* attnB = (u16*)(arena + 67108864);   // [B][8][256][256] bf16
  // encoder-phase arena views
  u16* qkvB = (u16*)arena;                 // [BN][768] bf16
  u16* ctxB = (u16*)(arena + 19660800);    // [BN][256] bf16
  u16* ffnB = (u16*)(arena + 26214400);    // [BN][512] bf16
  float* tmp = (float*)(arena + 39321600); // [BN][256] f32
  float* pref = (float*)arena;             // pointer phase

  // ---- prep ----
  prep_weights<<<dim3(512, 21), 256, 0, stream>>>(gat_W, enc_attn_W, enc_ffn_W1, enc_ffn_W2,
                                                  ptr_Wref, gatWT, WqkvT, WoT, W1T, W2T, WrefT);
  cast_bf16<<<3200, 256, 0, stream>>>(enc_inputs, encB, 819200);
  adj_transpose<<<dim3(7, 7, 64), 256, 0, stream>>>(adj, adjT);
  adj_bits<<<64, 256, 0, stream>>>(adj, adjW);

  // ---- GAT stack ----
  for (int g = 0; g < G_; ++g) {
    const u16* actB = (g == 0) ? encB : xbufB;
    const float* xin = (g == 0) ? enc_inputs : xbuf;
    gat_projT<<<dim3(16, 2, 64), 256, 0, stream>>>(gatWT + (size_t)g * 524288, actB, xpT);
    gat_attvec<<<512, 256, 0, stream>>>(xpT, gat_att_src + g * 2048, gat_att_dst + g * 2048,
                                        asrc, adst);
    gat_attn_softmax<<<BN_ * NH_, 64, 0, stream>>>(asrc, adst, adjT, attnB);
    gat_msg_mfma<<<dim3(2, 2, 64), 256, 0, stream>>>(attnB, xpT, gat_bias + g * H_, xin,
                                                     xbuf, xbufB);
  }
  ln_kernel<1><<<BN_, 256, 0, stream>>>(enc_inputs, xbuf, gat_ln, emb, embB);

  // ---- Transformer encoder ----
  for (int l = 0; l < L_; ++l) {
    gemm_bf16<0, true, false, true><<<dim3(100, 6), 256, 0, stream>>>(
        embB, WqkvT + (size_t)l * 196608, enc_attn_b + l * 1024, nullptr, nullptr, qkvB,
        BN_, 768, 256);
    attn_fused<<<512, 256, 0, stream>>>(qkvB, adjW, ctxB);
    gemm_bf16<0, true, true, false><<<dim3(100, 2), 256, 0, stream>>>(
        ctxB, WoT + (size_t)l * 65536, enc_attn_b + l * 1024 + 768, emb, tmp, nullptr,
        BN_, 256, 256);
    ln_kernel<0><<<BN_, 256, 0, stream>>>(tmp, nullptr, enc_ln1 + l * 512, emb, embB);
    gemm_bf16<1, true, false, true><<<dim3(100, 4), 256, 0, stream>>>(
        embB, W1T + (size_t)l * 131072, enc_ffn_b1 + l * 512, nullptr, nullptr, ffnB,
        BN_, 512, 256);
    gemm_bf16<0, true, true, false><<<dim3(100, 2), 256, 0, stream>>>(
        ffnB, W2T + (size_t)l * 131072, enc_ffn_b2 + l * 256, emb, tmp, nullptr,
        BN_, 256, 512);
    ln_kernel<0><<<BN_, 256, 0, stream>>>(tmp, nullptr, enc_ln2 + l * 512, emb, embB);
  }

  // ---- LSTM + pointer ----
  lstm_gates<<<256, 256, 0, stream>>>(dec_input, dec_h, lstm_Wih, lstm_Whh, lstm_b, gates);
  lstm_ew<<<64, 256, 0, stream>>>(gates, dec_c, h_out, c_out);
  hq_gemm<<<64, 256, 0, stream>>>(h_out, ptr_Wq, hq);
  gemm_bf16<0, false, false, false><<<dim3(100, 2), 256, 0, stream>>>(
      embB, WrefT, nullptr, nullptr, pref, nullptr, BN_, 256, 256);
  ptr_u<<<BN_, 64, 0, stream>>>(pref, hq, ptr_v, ubuf);
  policy_softmax<<<B_, 256, 0, stream>>>(ubuf, mask, policy);
}